// Round 21
// baseline (586.511 us; speedup 1.0000x reference)
//
#include <hip/hip_runtime.h>

// ---------------------------------------------------------------------------
// PanguProMoE decoder layer, MI355X (gfx950).
// Precision: qkv GEMM + QK^T in split-f16 (x = hi + lo/1024). Router logits
// via exact linear path with z-moments folded into the PV MFMA (R14).
// R21: dense GEMMs move to BN=64 tiles. Counter evidence (R20): qkv grid was
// 384 blocks at 2/CU capacity -> 128 CUs ran a single 4-wave block (Occ 15%,
// MfmaUtil 31%); o-proj 256 blocks = 1/CU. BN=64: qkv 768 blocks / 48KB LDS
// = exactly 3/CU, 100% fill, 12 waves/CU; o-proj 512 blocks / 24KB = 2/CU.
// Density 3:1 -> 2:1 MFMA:ds is a weak lever (R15: +1.5us); occupancy is the
// binding resource at 69% idle issue slots. Everything else = R17/R20 best:
// 4-warp KVBLK=64 attn (z in PV MFMA), BM=64 MoE GEMMs, GU ex[] LDS-union.
// ---------------------------------------------------------------------------

typedef _Float16 half_t;
typedef _Float16 half8 __attribute__((ext_vector_type(8)));
typedef _Float16 half2v __attribute__((ext_vector_type(2)));
typedef float    f32x4 __attribute__((ext_vector_type(4)));
typedef float    floatx4 __attribute__((ext_vector_type(4)));

#define T_TOK 2048
#define HIDN  2048
#define NH    16
#define NKVH  4
#define HD    128
#define QKV_N 3072
#define NEXP  8
#define NPAIR_MAX 4608   // 4096 pairs + 8*63 padding, 64-aligned

#define MFMA16(a,b,c) __builtin_amdgcn_mfma_f32_16x16x32_f16(a,b,c,0,0,0)

__device__ __forceinline__ void gload_lds16(const half_t* g, half_t* l) {
    __builtin_amdgcn_global_load_lds(
        (const __attribute__((address_space(1))) void*)g,
        (__attribute__((address_space(3))) void*)l, 16, 0, 0);
}

__device__ __forceinline__ float silu_f(float g) {
    return g / (1.0f + expf(-g));
}

// ---------------------------------------------------------------------------
// rmsnorm over HIDN cols, write split f16
// ---------------------------------------------------------------------------
__global__ __launch_bounds__(256)
void rmsnorm_split_k(const float* __restrict__ x, const float* __restrict__ w,
                     half_t* __restrict__ hi, half_t* __restrict__ lo)
{
    const int row = blockIdx.x, tid = threadIdx.x;
    const float* xr = x + (size_t)row * HIDN;
    floatx4 v0 = *(const floatx4*)(xr + tid * 8);
    floatx4 v1 = *(const floatx4*)(xr + tid * 8 + 4);
    float ss = v0[0]*v0[0] + v0[1]*v0[1] + v0[2]*v0[2] + v0[3]*v0[3]
             + v1[0]*v1[0] + v1[1]*v1[1] + v1[2]*v1[2] + v1[3]*v1[3];
    for (int o = 32; o; o >>= 1) ss += __shfl_down(ss, o);
    __shared__ float red[4];
    if ((tid & 63) == 0) red[tid >> 6] = ss;
    __syncthreads();
    ss = red[0] + red[1] + red[2] + red[3];
    float rs = rsqrtf(ss * (1.0f / HIDN) + 1e-6f);
    floatx4 w0 = *(const floatx4*)(w + tid * 8);
    floatx4 w1 = *(const floatx4*)(w + tid * 8 + 4);
    float vv[8] = { v0[0]*w0[0], v0[1]*w0[1], v0[2]*w0[2], v0[3]*w0[3],
                    v1[0]*w1[0], v1[1]*w1[1], v1[2]*w1[2], v1[3]*w1[3] };
    half8 hv, lv;
#pragma unroll
    for (int j = 0; j < 8; ++j) {
        float o = vv[j] * rs;
        half_t h = (half_t)o;
        hv[j] = h;
        lv[j] = (half_t)((o - (float)h) * 1024.0f);
    }
    *(half8*)(hi + (size_t)row * HIDN + tid * 8) = hv;
    if (lo) *(half8*)(lo + (size_t)row * HIDN + tid * 8) = lv;
}

// ---------------------------------------------------------------------------
// Transpose fp32 -> split f16: dst[n][k] = src[k][n]. 32x32 tile.
// ---------------------------------------------------------------------------
__global__ __launch_bounds__(256)
void transpose_split2(const float* __restrict__ src,
                      half_t* __restrict__ dh, half_t* __restrict__ dl,
                      int sstride, int dstride)
{
    __shared__ float tile[32][36];
    const int n0 = blockIdx.x * 32, k0 = blockIdx.y * 32;
    const int tid = threadIdx.x;
    {
        int r = tid >> 3, c = (tid & 7) * 4;
        *(floatx4*)&tile[r][c] =
            *(const floatx4*)(src + (size_t)(k0 + r) * sstride + n0 + c);
    }
    __syncthreads();
    int n = tid & 31, g = tid >> 5, gg = g & 3;
    half8 hv;
    if (g < 4) {
#pragma unroll
        for (int j = 0; j < 8; ++j) hv[j] = (half_t)tile[gg * 8 + j][n];
        *(half8*)(dh + (size_t)(n0 + n) * dstride + k0 + gg * 8) = hv;
    } else {
#pragma unroll
        for (int j = 0; j < 8; ++j) {
            float v = tile[gg * 8 + j][n];
            half_t h = (half_t)v;
            hv[j] = (half_t)((v - (float)h) * 1024.0f);
        }
        *(half8*)(dl + (size_t)(n0 + n) * dstride + k0 + gg * 8) = hv;
    }
}

// ---------------------------------------------------------------------------
// Transpose fp32 -> single f16: dst[n][k] = src[k][n]. 32(k)x64(n) tile.
// ---------------------------------------------------------------------------
__global__ __launch_bounds__(256)
void transpose_f16(const float* __restrict__ src, half_t* __restrict__ dh,
                   int sstride, int dstride)
{
    __shared__ float tile[32][68];
    const int n0 = blockIdx.x * 64, k0 = blockIdx.y * 32;
    const int tid = threadIdx.x;
    {
        int r = tid >> 3, c = (tid & 7) * 4;
        const float* s = src + (size_t)(k0 + r) * sstride + n0;
        *(floatx4*)&tile[r][c]      = *(const floatx4*)(s + c);
        *(floatx4*)&tile[r][c + 32] = *(const floatx4*)(s + c + 32);
    }
    __syncthreads();
    int n = tid & 63, g = tid >> 6;
    half8 hv;
#pragma unroll
    for (int j = 0; j < 8; ++j) hv[j] = (half_t)tile[g * 8 + j][n];
    *(half8*)(dh + (size_t)(n0 + n) * dstride + k0 + g * 8) = hv;
}

// ---------------------------------------------------------------------------
// V^T transpose, single f16, SIGMA-PERMUTED within each 32-token block:
// vt[d][32m + s] = V[32m + sigma_inv(s)][d], sigma_inv(s) = (s&1)*16 + (s>>1).
// ---------------------------------------------------------------------------
__global__ __launch_bounds__(256)
void vt_transpose_perm(const float* __restrict__ src, half_t* __restrict__ dh)
{
    __shared__ float tile[32][68];
    const int n0 = blockIdx.x * 64, k0 = blockIdx.y * 32;
    const int tid = threadIdx.x;
    {
        int r = tid >> 3, c = (tid & 7) * 4;
        const float* s = src + (size_t)(k0 + r) * QKV_N + n0;
        *(floatx4*)&tile[r][c]      = *(const floatx4*)(s + c);
        *(floatx4*)&tile[r][c + 32] = *(const floatx4*)(s + c + 32);
    }
    __syncthreads();
    int n = tid & 63, g = tid >> 6;
    half8 hv;
#pragma unroll
    for (int tt = 0; tt < 8; ++tt) {
        int c_src = (tt & 1) * 16 + 4 * g + (tt >> 1);
        hv[tt] = (half_t)tile[c_src][n];
    }
    *(half8*)(dh + (size_t)(n0 + n) * T_TOK + k0 + g * 8) = hv;
}

// ---------------------------------------------------------------------------
// Batched W13 transpose: W13t[n][k], n<10240:
//  [0,1024): sw1 | [1024,2048): sw3 | [2048,6144): w1[e] | [6144,10240): w3[e]
// ---------------------------------------------------------------------------
__global__ __launch_bounds__(256)
void w13_transpose(const float* __restrict__ sw1, const float* __restrict__ w1,
                   const float* __restrict__ sw3, const float* __restrict__ w3,
                   half_t* __restrict__ dst)
{
    __shared__ float tile[32][68];
    const int n0 = blockIdx.x * 64, k0 = blockIdx.y * 32;
    const int tid = threadIdx.x;
    const float* base;
    int stride;
    if (n0 < 1024)      { base = sw1 + n0; stride = 1024; }
    else if (n0 < 2048) { base = sw3 + (n0 - 1024); stride = 1024; }
    else if (n0 < 6144) { int e = (n0 - 2048) >> 9;
                          base = w1 + (size_t)e * HIDN * 512 + ((n0 - 2048) & 511);
                          stride = 512; }
    else                { int e = (n0 - 6144) >> 9;
                          base = w3 + (size_t)e * HIDN * 512 + ((n0 - 6144) & 511);
                          stride = 512; }
    {
        int r = tid >> 3, c = (tid & 7) * 4;
        const float* s = base + (size_t)(k0 + r) * stride;
        *(floatx4*)&tile[r][c]      = *(const floatx4*)(s + c);
        *(floatx4*)&tile[r][c + 32] = *(const floatx4*)(s + c + 32);
    }
    __syncthreads();
    int n = tid & 63, g = tid >> 6;
    half8 hv;
#pragma unroll
    for (int j = 0; j < 8; ++j) hv[j] = (half_t)tile[g * 8 + j][n];
    *(half8*)(dst + (size_t)(n0 + n) * HIDN + k0 + g * 8) = hv;
}

// ---------------------------------------------------------------------------
// Batched W2 transpose: W2t[n][k] (n<2048, k<5120), f16, dstride 5120.
// ---------------------------------------------------------------------------
__global__ __launch_bounds__(256)
void w2_transpose(const float* __restrict__ sw2, const float* __restrict__ w2,
                  half_t* __restrict__ dst)
{
    __shared__ float tile[32][68];
    const int n0 = blockIdx.x * 64, k0 = blockIdx.y * 32;
    const int tid = threadIdx.x;
    {
        int r = tid >> 3, c = (tid & 7) * 4;
        int k = k0 + r;
        const float* s;
        if (k < 1024) s = sw2 + (size_t)k * HIDN + n0;
        else {
            int e = (k - 1024) >> 9, kk = (k - 1024) & 511;
            s = w2 + ((size_t)e * 512 + kk) * HIDN + n0;
        }
        *(floatx4*)&tile[r][c]      = *(const floatx4*)(s + c);
        *(floatx4*)&tile[r][c + 32] = *(const floatx4*)(s + c + 32);
    }
    __syncthreads();
    int n = tid & 63, g = tid >> 6;
    half8 hv;
#pragma unroll
    for (int j = 0; j < 8; ++j) hv[j] = (half_t)tile[g * 8 + j][n];
    *(half8*)(dst + (size_t)(n0 + n) * 5120 + k0 + g * 8) = hv;
}

// ---------------------------------------------------------------------------
// ow_u[k][e] = sum_c o_w[k][c]*ln2w[c]*rw[c][e]. Also folds MoE meta init.
// ---------------------------------------------------------------------------
__global__ __launch_bounds__(256)
void owu_kernel(const float* __restrict__ ow, const float* __restrict__ ln2w,
                const float* __restrict__ rw, float* __restrict__ owu,
                int* __restrict__ cnt, int* __restrict__ pairTok,
                float* __restrict__ pairW)
{
    if (blockIdx.x < 18) {
        int idx = blockIdx.x * 256 + threadIdx.x;
        if (idx < NPAIR_MAX) { pairTok[idx] = 0; pairW[idx] = 0.0f; }
        if (idx < NEXP) cnt[idx] = 0;
    }
    const int k = blockIdx.x * 4 + (threadIdx.x >> 6);
    const int lane = threadIdx.x & 63;
    float acc[NEXP] = {};
    const float* row = ow + (size_t)k * HIDN;
#pragma unroll
    for (int j = 0; j < 8; ++j) {
        int c = j * 256 + lane * 4;
        floatx4 ov = *(const floatx4*)(row + c);
        floatx4 lw = *(const floatx4*)(ln2w + c);
#pragma unroll
        for (int i = 0; i < 4; ++i) {
            float s = ov[i] * lw[i];
            const float* rwc = rw + (size_t)(c + i) * NEXP;
#pragma unroll
            for (int e = 0; e < NEXP; ++e) acc[e] += s * rwc[e];
        }
    }
#pragma unroll
    for (int e = 0; e < NEXP; ++e)
        for (int o = 32; o; o >>= 1) acc[e] += __shfl_down(acc[e], o);
    if (lane == 0) {
#pragma unroll
        for (int e = 0; e < NEXP; ++e) owu[(size_t)k * NEXP + e] = acc[e];
    }
}

// ---------------------------------------------------------------------------
// z moments -> f16, sigma-permuted, V^T-style layout.
// ---------------------------------------------------------------------------
__global__ __launch_bounds__(256)
void z_kernel(const float* __restrict__ qkv, const float* __restrict__ owu,
              half_t* __restrict__ zt)
{
    const int kv = blockIdx.x, tid = threadIdx.x;
    const int hh = tid >> 4, li = tid & 15;
    const float* vrow = qkv + (size_t)kv * QKV_N + 2560 + (hh >> 2) * HD;
    const int d0 = li * 8;
    float acc[NEXP] = {};
#pragma unroll
    for (int j = 0; j < 8; ++j) {
        float v = vrow[d0 + j];
        const float* ou = owu + (size_t)(hh * HD + d0 + j) * NEXP;
#pragma unroll
        for (int e = 0; e < NEXP; ++e) acc[e] += v * ou[e];
    }
#pragma unroll
    for (int e = 0; e < NEXP; ++e)
        for (int o = 1; o < 16; o <<= 1) acc[e] += __shfl_xor(acc[e], o);
    if (li == 0) {
        int j = kv & 31;
        int s = ((j & 15) << 1) | (j >> 4);
        size_t base = (size_t)(kv & ~31) + s;
#pragma unroll
        for (int e = 0; e < NEXP; ++e)
            zt[(size_t)(hh * 8 + e) * T_TOK + base] = (half_t)acc[e];
    }
}

// ---------------------------------------------------------------------------
// GEMM: C[M][N] = A[M][K] @ Bt[N][K]^T (+bias)(+res). f16 in, fp32 acc.
// SPLIT: (hi, lo*1024) pairs, 3 MFMAs/tile. BM x BN tile, BK=32, 4 waves
// (2x2 warp grid over (BM/2, BN/2) sub-tiles). R21: BN templated; BN=64
// doubles the grid for 100% CU fill + higher block residency.
// ---------------------------------------------------------------------------
template<bool SPLIT, int BM, int BN>
__global__ __launch_bounds__(256, 2)
void gemm_f16(const half_t* __restrict__ Ah, const half_t* __restrict__ Al,
              const half_t* __restrict__ Bth, const half_t* __restrict__ Btl,
              const float* __restrict__ bias, const float* __restrict__ res,
              float* __restrict__ Cf, half_t* __restrict__ Ch,
              int M, int N, int K, int lda, int ldb)
{
    constexpr int NBUF = SPLIT ? 2 : 1;
    constexpr int MR = BM / 32;          // m-frags per warp
    constexpr int NR = BN / 32;          // n-frags per warp
    __shared__ half_t As[2][NBUF][BM * 32];
    __shared__ half_t Bs[2][NBUF][BN * 32];
    const int tid = threadIdx.x, lane = tid & 63, wid = tid >> 6;
    const int l15 = lane & 15, l4 = lane >> 4;
    const int row0 = blockIdx.y * BM, col0 = blockIdx.x * BN;
    const int wr = (wid >> 1) * (BM / 2), wc = (wid & 1) * (BN / 2);
    f32x4 accM[MR][NR] = {}, accC[MR][NR] = {};
    const int lrw = lane >> 2, lcl = (lane & 3) * 8;

#define STAGE(BUF, K0)                                                        \
    do {                                                                      \
        _Pragma("unroll")                                                     \
        for (int j = 0; j < BM / 64; ++j) {                                   \
            const int r = wid * (BM / 4) + j * 16;                            \
            const size_t ga = (size_t)(row0 + r + lrw) * lda + (K0) + lcl;    \
            gload_lds16(Ah + ga, &As[BUF][0][r * 32]);                        \
            if constexpr (SPLIT) gload_lds16(Al + ga, &As[BUF][1][r * 32]);   \
        }                                                                     \
        _Pragma("unroll")                                                     \
        for (int j = 0; j < BN / 64; ++j) {                                   \
            const int r = wid * (BN / 4) + j * 16;                            \
            const size_t gb = (size_t)(col0 + r + lrw) * ldb + (K0) + lcl;    \
            gload_lds16(Bth + gb, &Bs[BUF][0][r * 32]);                       \
            if constexpr (SPLIT) gload_lds16(Btl + gb, &Bs[BUF][1][r * 32]);  \
        }                                                                     \
    } while (0)

    STAGE(0, 0);
    __syncthreads();
    int cur = 0;
    for (int k0 = 0; k0 < K; k0 += 32, cur ^= 1) {
        if (k0 + 32 < K) STAGE(cur ^ 1, k0 + 32);
        half8 ah[MR], al[MR], bh[NR], bl[NR];
#pragma unroll
        for (int m = 0; m < MR; ++m) {
            int off = (wr + m * 16 + l15) * 32 + l4 * 8;
            ah[m] = *(const half8*)&As[cur][0][off];
            if constexpr (SPLIT) al[m] = *(const half8*)&As[cur][1][off];
        }
#pragma unroll
        for (int n = 0; n < NR; ++n) {
            int off = (wc + n * 16 + l15) * 32 + l4 * 8;
            bh[n] = *(const half8*)&Bs[cur][0][off];
            if constexpr (SPLIT) bl[n] = *(const half8*)&Bs[cur][1][off];
        }
#pragma unroll
        for (int m = 0; m < MR; ++m)
#pragma unroll
            for (int n = 0; n < NR; ++n) {
                accM[m][n] = MFMA16(ah[m], bh[n], accM[m][n]);
                if constexpr (SPLIT) {
                    accC[m][n] = MFMA16(ah[m], bl[n], accC[m][n]);
                    accC[m][n] = MFMA16(al[m], bh[n], accC[m][n]);
                }
            }
        __syncthreads();
    }
#undef STAGE

#pragma unroll
    for (int m = 0; m < MR; ++m) {
#pragma unroll
        for (int n = 0; n < NR; ++n) {
            int gr0 = row0 + wr + m * 16 + l4 * 4;
            int gc  = col0 + wc + n * 16 + l15;
            float b = bias ? bias[gc] : 0.0f;
#pragma unroll
            for (int i = 0; i < 4; ++i) {
                float v = accM[m][n][i];
                if constexpr (SPLIT) v += accC[m][n][i] * (1.0f / 1024.0f);
                v += b;
                size_t idx = (size_t)(gr0 + i) * N + gc;
                if (res) v += res[idx];
                if (Cf) Cf[idx] = v;
                if (Ch) Ch[idx] = (half_t)v;
            }
        }
    }
}

// ---------------------------------------------------------------------------
// Unified fused GU GEMM + silu act: one launch, 1088 blocks (BM=64).
// ex[] aliased onto As/Bs via union -- LDS 41.4 -> 24KB (R17).
// Safe: the final K-iteration ends with __syncthreads (all As/Bs reads and
// in-flight gload_lds drained) before ex is first written.
// ---------------------------------------------------------------------------
__global__ __launch_bounds__(256, 2)
void gemm_gu_all(const half_t* __restrict__ h2, const half_t* __restrict__ W13t,
                 const int* __restrict__ pairTok, const int* __restrict__ basep,
                 const float* __restrict__ pairW,
                 half_t* __restrict__ As_out, half_t* __restrict__ Ab_out)
{
    __shared__ union SM {
        struct { half_t As[2][64 * 32]; half_t Bs[2][128 * 32]; } s;  // 24KB
        half_t ex[64][136];                                           // 17.4KB
    } sm;
    const int bid = blockIdx.x;
    const bool grouped = (bid >= 512);
    int ct, row0;
    if (!grouped) { ct = bid & 15;          row0 = (bid >> 4) * 64; }
    else          { int g = bid - 512; ct = g & 7; row0 = (g >> 3) * 64; }
    const int tid = threadIdx.x, lane = tid & 63, wid = tid >> 6;
    const int l15 = lane & 15, l4 = lane >> 4;
    const int lrw = lane >> 2, lcl = (lane & 3) * 8;
    int gbase, ubase;
    if (grouped) {
        int e = 0;
#pragma unroll
        for (int i = 1; i < NEXP; ++i) if (row0 >= basep[i]) e = i;
        gbase = 2048 + 512 * e + ct * 64;
        ubase = 6144 + 512 * e + ct * 64;
    } else {
        gbase = ct * 64;
        ubase = 1024 + ct * 64;
    }
    const int wr = (wid >> 1) * 32, wc = (wid & 1) * 64;
    const half_t* Abase;
    if (grouped) {
        const int tok = pairTok[row0 + wid * 16 + lrw];
        Abase = h2 + (size_t)tok * HIDN + lcl;
    } else {
        Abase = h2 + (size_t)(row0 + wid * 16 + lrw) * HIDN + lcl;
    }
    f32x4 acc[2][4] = {};

#define GSTAGE(BUF, K0)                                                       \
    do {                                                                      \
        gload_lds16(Abase + (K0), &sm.s.As[BUF][(wid * 16) * 32]);            \
        _Pragma("unroll")                                                     \
        for (int j = 0; j < 2; ++j) {                                         \
            const int r = wid * 32 + j * 16;                                  \
            const int grow = (r < 64) ? gbase + r : ubase + (r - 64);         \
            const size_t gb = (size_t)(grow + lrw) * HIDN + (K0) + lcl;       \
            gload_lds16(W13t + gb, &sm.s.Bs[BUF][r * 32]);                    \
        }                                                                     \
    } while (0)

    GSTAGE(0, 0);
    __syncthreads();
    int cur = 0;
    for (int k0 = 0; k0 < HIDN; k0 += 32, cur ^= 1) {
        if (k0 + 32 < HIDN) GSTAGE(cur ^ 1, k0 + 32);
        half8 ah[2], bh[4];
#pragma unroll
        for (int m = 0; m < 2; ++m)
            ah[m] = *(const half8*)&sm.s.As[cur][(wr + m * 16 + l15) * 32 + l4 * 8];
#pragma unroll
        for (int n = 0; n < 4; ++n)
            bh[n] = *(const half8*)&sm.s.Bs[cur][(wc + n * 16 + l15) * 32 + l4 * 8];
#pragma unroll
        for (int m = 0; m < 2; ++m)
#pragma unroll
            for (int n = 0; n < 4; ++n)
                acc[m][n] = MFMA16(ah[m], bh[n], acc[m][n]);
        __syncthreads();
    }
#undef GSTAGE

    // epilogue: As/Bs fully drained by the last barrier -> reuse as ex
#pragma unroll
    for (int m = 0; m < 2; ++m)
#pragma unroll
        for (int n = 0; n < 4; ++n)
#pragma unroll
            for (int i = 0; i < 4; ++i)
                sm.ex[wr + m * 16 + l4 * 4 + i][wc + n * 16 + l15] =
                    (half_t)acc[m][n][i];
    __syncthreads();
    const int OSTR = grouped ? 512 : 1024;
    half_t* outp = grouped ? Ab_out : As_out;
#pragma unroll
    for (int w2 = 0; w2 < 2; ++w2) {
        int unit = tid * 2 + w2;
        int row = unit >> 3, cgx = (unit & 7) * 8;
        half8 g8 = *(const half8*)&sm.ex[row][cgx];
        half8 u8 = *(const half8*)&sm.ex[row][64 + cgx];
        float wgt = grouped ? pairW[row0 + row] : 1.0f;
        half8 o8;
#pragma unroll
        for (int j = 0; j < 8; ++j)
            o8[j] = (half_t)(silu_f((float)g8[j]) * (float)u8[j] * wgt);
        *(half8*)(outp + (size_t)(row0 + row) * OSTR + ct * 64 + cgx) = o8;
    }
}

// ---------------------------------------------------------------------------
// Fused down GEMM: grid (16, 104). by<32: shared (out = x2 + ...); else
// grouped (Ypair). BM=64 (R15).
// ---------------------------------------------------------------------------
__global__ __launch_bounds__(256, 2)
void gemm_down_all(const half_t* __restrict__ As_sh, const half_t* __restrict__ Ab,
                   const half_t* __restrict__ W2t, const int* __restrict__ basep,
                   const float* __restrict__ x2, float* __restrict__ out,
                   half_t* __restrict__ Ypair)
{
    __shared__ half_t Asm[2][64 * 32];
    __shared__ half_t Bsm[2][128 * 32];
    const int tid = threadIdx.x, lane = tid & 63, wid = tid >> 6;
    const int l15 = lane & 15, l4 = lane >> 4;
    const int lrw = lane >> 2, lcl = (lane & 3) * 8;
    const int col0 = blockIdx.x * 128;
    const bool shared = (blockIdx.y < 32);
    const int row0 = (shared ? blockIdx.y : blockIdx.y - 32) * 64;
    const half_t* A;
    int lda, K, bcol;
    if (shared) { A = As_sh; lda = 1024; K = 1024; bcol = 0; }
    else {
        int e = 0;
#pragma unroll
        for (int i = 1; i < NEXP; ++i) if (row0 >= basep[i]) e = i;
        A = Ab; lda = 512; K = 512; bcol = 1024 + 512 * e;
    }
    const int wr = (wid >> 1) * 32, wc = (wid & 1) * 64;
    f32x4 acc[2][4] = {};

#define DSTAGE(BUF, K0)                                                       \
    do {                                                                      \
        const size_t ga = (size_t)(row0 + wid * 16 + lrw) * lda + (K0) + lcl; \
        gload_lds16(A + ga, &Asm[BUF][(wid * 16) * 32]);                      \
        _Pragma("unroll")                                                     \
        for (int j = 0; j < 2; ++j) {                                         \
            const int r = wid * 32 + j * 16;                                  \
            const size_t gb = (size_t)(col0 + r + lrw) * 5120 + bcol + (K0) + lcl; \
            gload_lds16(W2t + gb, &Bsm[BUF][r * 32]);                         \
        }                                                                     \
    } while (0)

    DSTAGE(0, 0);
    __syncthreads();
    int cur = 0;
    for (int k0 = 0; k0 < K; k0 += 32, cur ^= 1) {
        if (k0 + 32 < K) DSTAGE(cur ^ 1, k0 + 32);
        half8 ah[2], bh[4];
#pragma unroll
        for (int m = 0; m < 2; ++m)
            ah[m] = *(const half8*)&Asm[cur][(wr + m * 16 + l15) * 32 + l4 * 8];
#pragma unroll
        for (int n = 0; n < 4; ++n)
            bh[n] = *(const half8*)&Bsm[cur][(wc + n * 16 + l15) * 32 + l4 * 8];
#pragma unroll
        for (int m = 0; m < 2; ++m)
#pragma unroll
            for (int n = 0; n < 4; ++n)
                acc[m][n] = MFMA16(ah[m], bh[n], acc[m][n]);
        __syncthreads();
    }
#undef DSTAGE

#pragma unroll
    for (int m = 0; m < 2; ++m)
#pragma unroll
        for (int n = 0; n < 4; ++n) {
            int gr0 = row0 + wr + m * 16 + l4 * 4;
            int gc  = col0 + wc + n * 16 + l15;
#pragma unroll
            for (int i = 0; i < 4; ++i) {
                size_t idx = (size_t)(gr0 + i) * HIDN + gc;
                if (shared) out[idx] = x2[idx] + acc[m][n][i];
                else        Ypair[idx] = (half_t)acc[m][n][i];
            }
        }
}

// ---------------------------------------------------------------------------
// qkv post-processing: k-rmsnorm, RoPE on q/k, Q pre-scaled, split-f16 out.
// ---------------------------------------------------------------------------
__global__ __launch_bounds__(256)
void qkv_prep(const float* __restrict__ qkv, const int* __restrict__ pos,
              const float* __restrict__ klnw,
              half_t* __restrict__ qh, half_t* __restrict__ ql,
              half_t* __restrict__ kh, half_t* __restrict__ kl)
{
    const int t = blockIdx.x, tid = threadIdx.x, lane = tid & 63, wid = tid >> 6;
    const float* row = qkv + (size_t)t * QKV_N;
    __shared__ float cs[32], sn[32];
    if (tid < 32) {
        double freq = exp((double)tid * -0.28782313662425572);  // -ln(1e4)/32
        double ang = (double)pos[t] * freq;
        const double twopi = 6.283185307179586476925286766559;
        ang -= twopi * floor(ang * (1.0 / twopi));
        float a = (float)ang;
        cs[tid] = cosf(a);
        sn[tid] = sinf(a);
    }
    __syncthreads();

    const float qscale = 0.08838834764831845f;   // 128^-0.5
    {
        const int hh = tid >> 4, d0 = (tid & 15) * 8;
        const float* qrow = row + hh * HD;
        float outv[8];
        if (d0 < 64) {
#pragma unroll
            for (int j = 0; j < 8; ++j) outv[j] = qrow[d0 + j];
        } else if (d0 < 96) {
            int j0 = d0 - 64;
#pragma unroll
            for (int j = 0; j < 8; ++j) {
                int jj = j0 + j;
                outv[j] = qrow[64 + jj] * cs[jj] - qrow[96 + jj] * sn[jj];
            }
        } else {
            int j0 = d0 - 96;
#pragma unroll
            for (int j = 0; j < 8; ++j) {
                int jj = j0 + j;
                outv[j] = qrow[64 + jj] * sn[jj] + qrow[96 + jj] * cs[jj];
            }
        }
        half8 hv, lv;
#pragma unroll
        for (int j = 0; j < 8; ++j) {
            float o = outv[j] * qscale;
            half_t h = (half_t)o;
            hv[j] = h;
            lv[j] = (half_t)((o - (float)h) * 1024.0f);
        }
        size_t base = (size_t)t * (NH * HD) + hh * HD + d0;
        *(half8*)(qh + base) = hv;
        *(half8*)(ql + base) = lv;
    }
    {
        const float* krow = row + NH * HD + wid * HD;
        float a0 = krow[lane], a1 = krow[64 + lane];
        float ss = a0 * a0 + a1 * a1;
        for (int o = 32; o; o >>= 1) ss += __shfl_down(ss, o);
        ss = __shfl(ss, 0);
        float rs = rsqrtf(ss * (1.0f / HD) + 1e-6f);
        float n0 = a0 * rs * klnw[lane];
        float n1 = a1 * rs * klnw[64 + lane];
        float other = __shfl_xor(n1, 32);
        int j = lane & 31;
        float o1 = (lane < 32) ? (n1 * cs[j] - other * sn[j])
                               : (other * sn[j] + n1 * cs[j]);
        size_t base = (size_t)t * (NKVH * HD) + wid * HD;
        half_t h;
        h = (half_t)n0; kh[base + lane] = h;
        kl[base + lane] = (half_t)((n0 - (float)h) * 1024.0f);
        h = (half_t)o1; kh[base + 64 + lane] = h;
        kl[base + 64 + lane] = (half_t)((o1 - (float)h) * 1024.0f);
    }
}

// ---------------------------------------------------------------------------
// Chunked flash attention, causal GQA, KVBLK=64. QK^T split-f16; PV single-
// f16 with sigma-permuted V. z-moments ride the PV MFMA (Vsh rows 128-135);
// om[8] accumulates zacc; rows 136-143 unstaged garbage, outputs unread.
// ---------------------------------------------------------------------------
__global__ __launch_bounds__(256, 2)
void attn_kernel(const half_t* __restrict__ qh, const half_t* __restrict__ ql,
                 const half_t* __restrict__ kh, const half_t* __restrict__ kl,
                 const half_t* __restrict__ vth, const half_t* __restrict__ zt,
                 half_t* __restrict__ oh,
                 float* __restrict__ Op0, float* __restrict__ Op1,
                 float* __restrict__ Op2, float* __restrict__ ml,
                 float* __restrict__ zpart, float* __restrict__ zfin)
{
    const int bid = blockIdx.x;
    const int h = bid & 15;
    int rrem = bid >> 4, q = 31, nch = 6, c = 0;
    for (; q >= 0; --q) {
        nch = (q + 6) / 6;
        if (rrem < nch) { c = rrem; break; }
        rrem -= nch;
    }
    const int nt = q + 1;                        // 64-wide kv tiles
    const int kvbeg = ((c * nt) / nch) * 64;
    const int kvend = (((c + 1) * nt) / nch) * 64;

    const int kvh = h >> 2;
    const int tid = threadIdx.x, lane = tid & 63, wid = tid >> 6;
    const int q0 = q * 64 + wid * 16;
    const int l15 = lane & 15, l4 = lane >> 4;

    __shared__ half_t Ksh[64][136], Ksl[64][136];
    __shared__ half_t Vsh[144][72];              // rows 128-135: z (f16)
    __shared__ half_t Ph[4][16][72];

    half8 qfh[4], qfl[4];
    {
        const size_t qb = (size_t)(q0 + l15) * (NH * HD) + h * HD + l4 * 8;
#pragma unroll
        for (int cc = 0; cc < 4; ++cc) {
            qfh[cc] = *(const half8*)(qh + qb + cc * 32);
            qfl[cc] = *(const half8*)(ql + qb + cc * 32);
        }
    }

    f32x4 om[9] = {};                            // om[8] = z accumulator
    float mrow[4] = { -1e30f, -1e30f, -1e30f, -1e30f };
    float lrow[4] = {};

    const int kr = tid >> 2, kc0 = (tid & 3) * 32;
    const int vd = tid >> 1, vc0 = (tid & 1) * 32;
    const int ze = tid >> 5, zc0 = (tid & 31) * 2;
    uint4 rkh0, rkh1, rkh2, rkh3, rkl0, rkl1, rkl2, rkl3;
    uint4 rv0, rv1, rv2, rv3;
    unsigned rzw;

#define LOAD_TILE(KV0)                                                        \
    do {                                                                      \
        size_t sk = (size_t)((KV0) + kr) * (NKVH * HD) + kvh * HD + kc0;      \
        rkh0 = *(const uint4*)(kh + sk);       rkl0 = *(const uint4*)(kl + sk);      \
        rkh1 = *(const uint4*)(kh + sk + 8);   rkl1 = *(const uint4*)(kl + sk + 8);  \
        rkh2 = *(const uint4*)(kh + sk + 16);  rkl2 = *(const uint4*)(kl + sk + 16); \
        rkh3 = *(const uint4*)(kh + sk + 24);  rkl3 = *(const uint4*)(kl + sk + 24); \
        size_t sv = (size_t)(kvh * HD + vd) * T_TOK + (KV0) + vc0;            \
        rv0 = *(const uint4*)(vth + sv);       rv1 = *(const uint4*)(vth + sv + 8);  \
        rv2 = *(const uint4*)(vth + sv + 16);  rv3 = *(const uint4*)(vth + sv + 24); \
        rzw = *(const unsigned*)(zt + (size_t)(h * 8 + ze) * T_TOK + (KV0) + zc0);   \
    } while (0)

    LOAD_TILE(kvbeg);
    for (int kv0 = kvbeg; kv0 < kvend; kv0 += 64) {
        *(uint4*)&Ksh[kr][kc0]      = rkh0;  *(uint4*)&Ksl[kr][kc0]      = rkl0;
        *(uint4*)&Ksh[kr][kc0 + 8]  = rkh1;  *(uint4*)&Ksl[kr][kc0 + 8]  = rkl1;
        *(uint4*)&Ksh[kr][kc0 + 16] = rkh2;  *(uint4*)&Ksl[kr][kc0 + 16] = rkl2;
        *(uint4*)&Ksh[kr][kc0 + 24] = rkh3;  *(uint4*)&Ksl[kr][kc0 + 24] = rkl3;
        *(uint4*)&Vsh[vd][vc0]      = rv0;   *(uint4*)&Vsh[vd][vc0 + 8]  = rv1;
        *(uint4*)&Vsh[vd][vc0 + 16] = rv2;   *(uint4*)&Vsh[vd][vc0 + 24] = rv3;
        *(unsigned*)&Vsh[128 + ze][zc0] = rzw;
        __syncthreads();
        if (kv0 + 64 < kvend) LOAD_TILE(kv0 + 64);   // hides under compute

        f32x4 sf[4];
        __builtin_amdgcn_s_setprio(1);
#pragma unroll
        for (int t2 = 0; t2 < 4; ++t2) {       // S = Q K^T (pre-scaled Q)
            f32x4 s = {}, sc1 = {}, sc2 = {};
#pragma unroll
            for (int cc = 0; cc < 4; ++cc) {
                half8 bh = *(const half8*)&Ksh[t2 * 16 + l15][cc * 32 + l4 * 8];
                half8 bl = *(const half8*)&Ksl[t2 * 16 + l15][cc * 32 + l4 * 8];
                s   = MFMA16(qfh[cc], bh, s);
                sc1 = MFMA16(qfh[cc], bl, sc1);
                sc2 = MFMA16(qfl[cc], bh, sc2);
            }
            sf[t2] = s + (sc1 + sc2) * (1.0f / 1024.0f);
        }
        __builtin_amdgcn_s_setprio(0);

        float pmax[4];
#pragma unroll
        for (int i = 0; i < 4; ++i) {
            const int qg = q0 + l4 * 4 + i;
#pragma unroll
            for (int t2 = 0; t2 < 4; ++t2) {
                int kvg = kv0 + t2 * 16 + l15;
                if (kvg > qg) sf[t2][i] = -1e30f;
            }
            float mx = fmaxf(fmaxf(sf[0][i], sf[1][i]),
                             fmaxf(sf[2][i], sf[3][i]));
#pragma unroll
            for (int o = 1; o < 16; o <<= 1) mx = fmaxf(mx, __shfl_xor(mx, o));
            pmax[i] = mx;
        }
        float dm = fmaxf(fmaxf(pmax[0] - mrow[0], pmax[1] - mrow[1]),
                         fmaxf(pmax[2] - mrow[2], pmax[3] - mrow[3]));
        if (__any(dm > 6.0f)) {                // defer-max
#pragma unroll
            for (int i = 0; i < 4; ++i) {
                float mnew = fmaxf(mrow[i], pmax[i]);
                float resc = expf(mrow[i] - mnew);
                lrow[i] *= resc;
#pragma unroll
                for (int c8 = 0; c8 < 9; ++c8) om[c8][i] *= resc;
                mrow[i] = mnew;
            }
        }
#pragma unroll
        for (int i = 0; i < 4; ++i) {
            float p0 = expf(sf[0][i] - mrow[i]);
            float p1 = expf(sf[1][i] - mrow[i]);
            float p2 = expf(sf[2][i] - mrow[i]);
            float p3 = expf(sf[3][i] - mrow[i]);
            lrow[i] += (p0 + p1) + (p2 + p3);
            half2v ppA = { (half_t)p0, (half_t)p1 };   // sigma-interleaved
            half2v ppB = { (half_t)p2, (half_t)p3 };
            *(half2v*)&Ph[wid][l4 * 4 + i][l15 * 2]      = ppA;
            *(half2v*)&Ph[wid][l4 * 4 + i][32 + l15 * 2] = ppB;
        }

        half8 pa0 = *(const half8*)&Ph[wid][l15][l4 * 8];
        half8 pa1 = *(const half8*)&Ph[wid][l15][32 + l4 * 8];
        __builtin_amdgcn_s_setprio(1);
#pragma unroll
        for (int c8 = 0; c8 < 9; ++c8) {       // O += P V ; om[8] += P z
            half8 v0 = *(const half8*)&Vsh[c8 * 16 + l15][l4 * 8];
            half8 v1 = *(const half8*)&Vsh[c8 * 16 + l15][32 + l4 * 8];
            om[c8] = MFMA16(pa0, v0, om[c8]);
            om[c8] = MFMA16(pa1, v1, om[c8]);
        }
        __builtin_amdgcn_s_setprio(0);
        __syncthreads();
    }
#undef LOAD_TILE

#pragma unroll
    for (int i = 0; i < 4; ++i)
#pragma unroll
        for (int o = 1; o < 16; o <<= 1) lrow[i] += __shfl_xor(lrow[i], o);

    if (l15 < 8) {
        const int e = l15;
#pragma unroll
        for (int i = 0; i < 4; ++i) {
            int row64 = wid * 16 + l4 * 4 + i;
            if (nch == 1) {
                zfin[((size_t)(q * 64 + row64) * 16 + h) * 8 + e] =
                    om[8][i] / lrow[i];
            } else {
                zpart[((size_t)bid * 64 + row64) * 8 + e] = om[8][i];
            }
        }
    }

    if (nch == 1) {
#pragma unroll
        for (int c8 = 0; c8 < 8; ++c8) {
#pragma unroll
            for (int i = 0; i < 4; ++i) {
                float v = om[c8][i] / lrow[i];
                size_t idx = (size_t)(q0 + l4 * 4 + i) * (NH * HD) + h * HD
                           + c8 * 16 + l15;
                oh[idx] = (half_t)v;
            }
        }
    } else {
        float* Op = (bid < 768)  ? Op0 + (size_t)bid * 8192
                  : (bid < 1280) ? Op1 + (size_t)(bid - 768) * 8192
                                 : Op2 + (size_t)(bid - 1280) * 8192;
#pragma unroll
        for (int c8 = 0; c8 < 8; ++c8) {
#pragma unroll
            for (int i = 0; i < 4; ++i) {
                int row64 = wid * 16 + l4 * 4 + i;
                Op[row64 * 128 + c8 * 16 + l15] = om[c8][i];
            }
        }
        if (l15 == 0) {
#pragma unroll
            for (int i = 0; i < 4; ++i) {
                int row64 = wid * 16 + l4 * 4 + i;
                ml[(size_t)bid * 128 + row64]      = mrow[i];
                ml[(size_t)bid * 128 + 64 + row64] = lrow[i];
            }
        }
    }
}

// ---------------------------------------------------------------------------
// Combine partial attention chunks (q >= 6): O merge + z-moment merge.
// ---------------------------------------------------------------------------
__device__ __forceinline__ const float* slot_ptr(int s, const float* Op0,
                                                 const float* Op1,
                                                 const float* Op2)
{
    return (s < 768)  ? Op0 + (size_t)s * 8192
         : (s < 1280) ? Op1 + (size_t)(s - 768) * 8192
                      : Op2 + (size_t)(s - 1280) * 8192;
}

__global__ __launch_bounds__(256)
void attn_combine(const float* __restrict__ Op0, const float* __restrict__ Op1,
                  const float* __restrict__ Op2, const float* __restrict__ ml,
                  const float* __restrict__ zpart,
                  half_t* __restrict__ oh, float* __restrict__ zfin)
{
    const int bid = blockIdx.x;
    const int h = bid & 15, q = 6 + (bid >> 4);
    const int nch = (q + 6) / 6;
    int r0 = 0;
    for (int j = 31; j > q; --j) r0 += (j + 6) / 6;
    const int tid = threadIdx.x;
    const int row = tid >> 2, cg = (tid & 3) * 32;

    float M = -1e30f;
    for (int c = 0; c < nch; ++c) {
        int s = (r0 + c) * 16 + h;
        M = fmaxf(M, ml[(size_t)s * 128 + row]);
    }
    float wsum = 0.0f;
    for (int c = 0; c < nch; ++c) {
        int s = (r0 + c) * 16 + h;
        wsum += ml[(size_t)s * 128 + 64 + row] *
                expf(ml[(size_t)s * 128 + row] - M);
    }
    float inv = 1.0f / wsum;

    if ((tid & 3) == 0) {
        f32x4 a = {0,0,0,0}, b = {0,0,0,0};
        for (int c = 0; c < nch; ++c) {
            int s = (r0 + c) * 16 + h;
            float w = expf(ml[(size_t)s * 128 + row] - M) * inv;
            size_t zo = ((size_t)s * 64 + row) * 8;
            a += w * (*(const f32x4*)&zpart[zo]);
            b += w * (*(const f32x4*)&zpart[zo + 4]);
        }
        size_t zo = ((size_t)(q * 64 + row) * 16 + h) * 8;
        *(f32x4*)&zfin[zo]     = a;
        *(f32x4*)&zfin[zo + 4] = b;
    }

    size_t obase = (size_t)(q * 64 + row) * (NH * HD) + h * HD + cg;
#pragma unroll
    for (int jj = 0; jj < 4; ++jj) {
        floatx4 a0 = {0,0,0,0}, a1 = {0,0,0,0};
        for (int c = 0; c < nch; ++c) {
            int s = (r0 + c) * 16 + h;
            float w = expf(ml[(size_t)s * 128 + row] - M) * inv;
            const float* base = slot_ptr(s, Op0, Op1, Op2) + row * 128 + cg;
            a0 += w * (*(const floatx4*)(base + jj * 8));
            a1 += w * (*(const floatx4*)(base + jj * 8 + 4));
        }
        half8 hv;
#pragma unroll
        for (int k = 0; k < 4; ++k) {
            hv[k]     = (half_t)a0[k];
            hv[4 + k] = (half_t)a1[k];
        }
        *(half8*)(oh + obase + jj * 8) = hv;
    }
}

// ---------------------------------------------------------------------------
// Linear router: logit_e = rs(x2)*(x.u_e + sum_h zfin[t][h][e]).
// Writes top-2 + histogram + h2 = rmsnorm(x2, ln2w).
// ---------------------------------------------------------------------------
__global__ __launch_bounds__(256)
void router_linear(const float* __restrict__ x, const float* __restrict__ zfin,
                   const float* __restrict__ x2,
                   const float* __restrict__ ln2w, const float* __restrict__ rw,
                   int* __restrict__ topi, float* __restrict__ topv,
                   int* __restrict__ cnt, half_t* __restrict__ h2)
{
    const int t = blockIdx.x, tid = threadIdx.x;
    const float* xr2 = x2 + (size_t)t * HIDN + tid * 8;
    floatx4 x2a = *(const floatx4*)(xr2);
    floatx4 x2b = *(const floatx4*)(xr2 + 4);
    float ss = x2a[0]*x2a[0] + x2a[1]*x2a[1] + x2a[2]*x2a[2] + x2a[3]*x2a[3]
             + x2b[0]*x2b[0] + x2b[1]*x2b[1] + x2b[2]*x2b[2] + x2b[3]*x2b[3];
    for (int o = 32; o; o >>= 1) ss += __shfl_down(ss, o);
    __shared__ float red[4];
    if ((tid & 63) == 0) red[tid >> 6] = ss;
    __syncthreads();
    ss = red[0] + red[1] + red[2] + red[3];
    float rs = rsqrtf(ss * (1.0f / HIDN) + 1e-6f);

    const float* xr = x + (size_t)t * HIDN + tid * 8;
    floatx4 xa = *(const floatx4*)(xr);
    floatx4 xb = *(const floatx4*)(xr + 4);
    floatx4 lwa = *(const floatx4*)(ln2w + tid * 8);
    floatx4 lwb = *(const floatx4*)(ln2w + tid * 8 + 4);

    float acc[NEXP] = {};
#pragma unroll
    for (int j = 0; j < 8; ++j) {
        int c = tid * 8 + j;
        float xv = (j < 4 ? xa[j] : xb[j - 4]) * (j < 4 ? lwa[j] : lwb[j - 4]);
        const float* rwc = rw + (size_t)c * NEXP;
#pragma unroll
        for (int e = 0; e < NEXP; ++e) acc[e] += xv * rwc[e];
    }
#pragma unroll
    for (int e = 0; e < NEXP; ++e)
        for (int o = 32; o; o >>= 1) acc[e] += __shfl_down(acc[e], o);
    __shared__ float red8[4][NEXP];
    if ((tid & 63) == 0)
#pragma unroll
        for (int e = 0; e < NEXP; ++e) red8[tid >> 6][e] = acc[e];

    __shared__ float zred[NEXP * 16];
    if (tid < 128) {
        int hh = tid >> 3, e = tid & 7;
        zred[e * 16 + hh] = zfin[((size_t)t * 16 + hh) * 8 + e];
    }

    half8 h2v;
#pragma unroll
    for (int j = 0; j < 8; ++j) {
        float xv = (j < 4 ? x2a[j] : x2b[j - 4]) * (j < 4 ? lwa[j] : lwb[j - 4]);
        h2v[j] = (half_t)(xv * rs);
    }
    *(half8*)(h2 + (size_t)t * HIDN + tid * 8) = h2v;

    __syncthreads();
    if (tid == 0) {
        float lg[NEXP];
#pragma unroll
        for (int e = 0; e < NEXP; ++e) {
            float zs = 0.0f;
#pragma unroll
            for (int hh = 0; hh < 16; ++hh) zs += zred[e * 16 + hh];
            lg[e] = (red8[0][e] + red8[1][e] + red8[2][e] + red8[3][e] + zs) * rs;
        }
        int i1 = 0;
        for (int e = 1; e < NEXP; ++e) if (lg[e] > lg[i1]) i1 = e;
        int i2 = (i1 == 0) ? 1 : 0;
        for (int e = 0; e < NEXP; ++e) if (e != i1 && lg[e] > lg[i2]) i2 = e;
        float mx = lg[i1];
        float p1 = expf(lg[i1] - mx), p2 = expf(lg[i2] - mx);
        float inv = 1.0f / (p1 + p2);
        topi[2 * t] = i1;       topi[2 * t + 1] = i2;
        topv[2 * t] = p1 * inv; topv[2 * t + 1] = p2 * inv;
        atomicAdd(&cnt[i1], 1);
        atomicAdd(&cnt[i2], 1);
    }
}

// ---------------------------------------------------------------------------
// Deterministic pair-list build (ballot prefix scan), 64-aligned regions.
// ---------------------------------------------------------------------------
__global__ __launch_bounds__(256)
void moe_build(const int* __restrict__ cnt, int* __restrict__ basep,
               const int* __restrict__ topi, const float* __restrict__ topv,
               int* __restrict__ pairTok, float* __restrict__ pairW,
               int* __restrict__ pairPos)
{
    const int e = blockIdx.x;
    int base = 0;
    for (int i = 0; i < e; ++i) base += (cnt[i] + 63) & ~63;
    if (threadIdx.x == 0) basep[e] = base;

    const int tid = threadIdx.x, lane = tid & 63, wv = tid >> 6;
    __shared__ int wsum[4];
    int run = base;
    for (int i0 = 0; i0 < 2 * T_TOK; i0 += 256) {
        int i = i0 + tid;
        bool m = (topi[i] == e);
        unsigned long long bal = __ballot(m);
        int lpre = __popcll(bal & ((1ull << lane) - 1ull));
        if (lane == 0) wsum[wv] = (int)__popcll(bal);
        __syncthreads();
        int woff = 0;
        for (int w = 0; w < wv; ++w) woff += wsum[w];
        if (m) {
            int pos = run + woff + lpre;
            pairTok[pos] = i >> 1;
            pairW[pos]   = topv[i];
            pairPos[i]   = pos;
        }
        run += wsum[0] + wsum[1] + wsum[2] + wsum[3];
        __syncthreads();
    }
}

// ---------------------------------------------------------------------------
// Final: out[t] += Ypair[p1] + Ypair[p2]
// ---------------------------------------------------------------------------
__global__ __launch_bounds__(256)
void moe_final(const half_t* __restrict__ Ypair, const int* __restrict__ pairPos,
               float* __restrict__ out)
{
    int t = blockIdx.x, c0 = threadIdx.x * 8;
    int p1 = pairPos[2 * t], p2 = pairPos[2 * t + 1];
    half8 y1 = *(const half8*)(Ypair + (size_t)p1 * HIDN + c0);
    half8 y2 = *(const half8*)(Ypair + (size_t)p2 * HIDN + c0);
    float* o = out + (size_t)t * HIDN + c0;
    floatx4 a = *(floatx4*)o, b = *(floatx4*)(o + 4);
#pragma unroll
    for (int j = 0; j < 4; ++j) {
        a[j] += (float)y1[j] + (float)y2[j];
        b[j] += (float)y1[4 + j] + (float)y2[4 + j];
    }
    *(floatx4*)o = a;
    *(floatx4*)(o + 4) = b;
}

// ---------------------------------------------------------------------------
extern "C" void kernel_launch(void* const* d_in, const int* in_sizes, int n_in,
                              void* d_out, int out_size, void* d_ws, size_t ws_size,
                              hipStream_t stream)
{
    (void)in_sizes; (void)n_in; (void)out_size; (void)ws_size;
    const float* x    = (const float*)d_in[0];
    const int*   pos  = (const int*)  d_in[1];
    const float* ln1w = (const float*)d_in[2];
    const float* qkvw = (const float*)d_in[3];
    const float* qkvb = (const float*)d_in[4];
    const float* klnw = (const float*)d_in[5];
    const float* ow   = (const float*)d_in[6];
    const float* ln2w = (const float*)d_in[7];
    const float* rw   = (const float*)d_in[8];
    const float* w1   = (const float*)d_in[9];
    const float* w2   = (const float*)d_in[10];
    const float* w3   = (const float*)d_in[11];
    const float* sw1  = (const float*)d_in[12];
    const float* sw2  = (const float*)d_in[13];
    const float* sw3  = (const float*)d_in[14];
    float* out = (float*)d_out;

    // ---- workspace arena (phase-overlapped; within proven 142.7 MB) ----
    char* ws = (char*)d_ws;
    const size_t AB = 16842752;
    float*  x2      = (float*)(ws);                   // also Opart1 (512 slots)
    half_t* h_hi    = (half_t*)(ws + AB);
    half_t* h_lo    = (half_t*)(ws + AB + 8388608);
    half_t* qkvwt_h = (half_t*)(ws + AB + 16777216);
    half_t* qkvwt_l = (half_t*)(ws + AB + 29360128);
    float*  qkv     = (float*)(ws + AB + 41943040);   // also Opart0 / W13t
    half_t* q_h     = (half_t*)(ws + AB + 67108864);
    half_t* q_l     = (half_t*)(ws + AB + 75497472);
    half_t* k_h     = (half_t*)(ws + AB + 83886080);
    half_t* k_l     = (half_t*)(ws + AB + 85983232);
    half_t* vt_h    = (half_t*)(ws + AB + 88080384);
    half_t* attn_h  = (half_t*)(ws + AB);             // reuse h_hi
    half_t* zt      = (half_t*)(ws + AB + 8388608);   // reuse h_lo (512 KB, f16)
    half_t* owt     = (half_t*)(ws + AB + 16777216);  // reuse qkvwt_h
    float*  ow_u    = (float*)(ws + AB + 25165824);   // 64 KB
    float*  mlpart  = (float*)(ws + AB + 25231360);   // 836 KB
    float*  Opart0  = (float*)(ws + AB + 41943040);   // qkv region, 768 slots
    float*  Opart1  = (float*)(ws);                   // x2 region, 512 slots
    float*  Opart2  = (float*)(ws + AB + 29360128);   // qkvwt_l region, 352 slots
    half_t* h2      = (half_t*)(ws + AB + 33554432);  // 8.4MB
    half_t* W13t    = (half_t*)(ws + AB + 41943040);  // 41.9MB (qkv+q dead)
    half_t* As_sh   = (half_t*)(ws + AB);             // 4.2MB (attn dead post-x2)
    half_t* Ab      = (half_t*)(ws + AB + 16777216);  // 4.7MB (owt dead)
    half_t* W2t     = (half_t*)(ws + AB + 41943040);  // 21MB (W13t dead post-GU)
    half_t* Ypair   = (half_t*)(ws + AB + 92274688);  // 18.9MB

    // ---- tail block: meta (~86KB) + zpart (3.34MB) + zfin (1MB) ----
    char* meta = ws + (size_t)(AB + 117440512);
    int*    cnt     = (int*)  (meta + 0);
    int*    basep   = (int*)  (meta + 128);
    int*    topi    = (int*)  (meta + 256);
    float*  topv    = (float*)(meta + 16640);
    int*    pairPos = (int*)  (meta + 33024);
    int*    pairTok = (int*)  (meta + 49408);
    float*  pairW   = (float*)(meta + 67840);
    float*  zpart   = (float*)(meta + 131072);        // 3342336 B
    float*  zfin    = (float*)(meta + 131072 + 3342336); // 1 MB

    dim3 b256(256);

    // 1. h = rmsnorm(x, ln1_w) split
    rmsnorm_split_k<<<T_TOK, b256, 0, stream>>>(x, ln1w, h_hi, h_lo);
    // 2. qkv_w -> transposed split f16
    transpose_split2<<<dim3(QKV_N / 32, HIDN / 32), b256, 0, stream>>>(
        qkvw, qkvwt_h, qkvwt_l, QKV_N, HIDN);
    // 3. qkv = h @ qkv_w + b  (split path, BM=128 x BN=64: 768 blocks, 3/CU)
    gemm_f16<true, 128, 64><<<dim3(QKV_N / 64, T_TOK / 128), b256, 0, stream>>>(
        h_hi, h_lo, qkvwt_h, qkvwt_l, qkvb, nullptr, qkv, nullptr,
        T_TOK, QKV_N, HIDN, HIDN, HIDN);
    // 4. k-rmsnorm + rope + split (q pre-scaled)
    qkv_prep<<<T_TOK, b256, 0, stream>>>(qkv, pos, klnw, q_h, q_l, k_h, k_l);
    // 5. v^T single f16, sigma-permuted
    vt_transpose_perm<<<dim3(512 / 64, T_TOK / 32), b256, 0, stream>>>(
        qkv + 2560, vt_h);
    // 6. o_w transpose (single f16)
    transpose_f16<<<dim3(HIDN / 64, HIDN / 32), b256, 0, stream>>>(
        ow, owt, HIDN, HIDN);
    // 7. ow_u = o_w @ (ln2w * rw)  (+ folded moe_init)
    owu_kernel<<<512, b256, 0, stream>>>(ow, ln2w, rw, ow_u,
                                         cnt, pairTok, pairW);
    // 7b. z moments -> f16 sigma-permuted zt[h*8+e][kv]
    z_kernel<<<T_TOK, b256, 0, stream>>>(qkv, ow_u, zt);
    // 8. attention (chunked, KVBLK=64, z folded into PV MFMA)
    attn_kernel<<<1632, b256, 0, stream>>>(
        q_h, q_l, k_h, k_l, vt_h, zt, attn_h,
        Opart0, Opart1, Opart2, mlpart, zpart, zfin);
    // 8b. combine partial chunks (O + z)
    attn_combine<<<416, b256, 0, stream>>>(Opart0, Opart1, Opart2, mlpart,
                                           zpart, attn_h, zfin);
    // 9. x2 = x + attn @ o_w  (single f16, BM=128 x BN=64: 512 blocks, 2/CU)
    gemm_f16<false, 128, 64><<<dim3(HIDN / 64, T_TOK / 128), b256, 0, stream>>>(
        attn_h, nullptr, owt, nullptr, nullptr, x, x2, nullptr,
        T_TOK, HIDN, HIDN, HIDN, HIDN);
    // 10. router (x.u + z moments) -> top-2 + h2
    router_linear<<<T_TOK, b256, 0, stream>>>(
        x, zfin, x2, ln2w, rw, topi, topv, cnt, h2);
    // 10b. deterministic pair-list build
    moe_build<<<NEXP, b256, 0, stream>>>(cnt, basep, topi, topv,
                                         pairTok, pairW, pairPos);
    // 11. W13t batched transpose
    w13_transpose<<<dim3(10240 / 64, HIDN / 32), b256, 0, stream>>>(
        sw1, w1, sw3, w3, W13t);
    // 12. fused GU + act, BM=64, shared + grouped in ONE launch (1088 blocks)
    gemm_gu_all<<<512 + 8 * (NPAIR_MAX / 64), b256, 0, stream>>>(
        h2, W13t, pairTok, basep, pairW, As_sh, Ab);
    // 13. W2t batched transpose
    w2_transpose<<<dim3(HIDN / 64, 5120 / 32), b256, 0, stream>>>(sw2, w2, W2t);
    // 14. fused down, BM=64 (shared -> out, grouped -> Ypair), grid (16,104)
    gemm_down_all<<<dim3(16, 104), b256, 0, stream>>>(
        As_sh, Ab, W2t, basep, x2, out, Ypair);
    // 15. out += Ypair[p1] + Ypair[p2]
    moe_final<<<T_TOK, b256, 0, stream>>>(Ypair, pairPos, out);
}

// Round 22
// 579.090 us; speedup vs baseline: 1.0128x; 1.0128x over previous
//
#include <hip/hip_runtime.h>

// ---------------------------------------------------------------------------
// PanguProMoE decoder layer, MI355X (gfx950). FINAL (= R17/R20 best, 579.4us).
// Precision: qkv GEMM + QK^T in split-f16 (x = hi + lo/1024). Router logits
// via exact linear path with z-moments folded into the PV MFMA.
// Ledger: R16 (MoE BM=128) -22us tail/residency; R18/R19 (8-warp attn) -30us
// barrier+VGPR residency; R21 (dense BN=64) -7us: occupancy 15->30% did NOT
// move MfmaUtil (30%) -- dense split-GEMM is 2-phase barrier-drain structure
// bound at ~750 TF effective across all tile configs. This config: BM=128
// BN=128 dense GEMMs, 4-warp KVBLK=64 attn (z in PV MFMA), BM=64 MoE GEMMs,
// GU ex[] LDS-union (24KB). All MFMA kernels at min-waves/EU=2.
// ---------------------------------------------------------------------------

typedef _Float16 half_t;
typedef _Float16 half8 __attribute__((ext_vector_type(8)));
typedef _Float16 half2v __attribute__((ext_vector_type(2)));
typedef float    f32x4 __attribute__((ext_vector_type(4)));
typedef float    floatx4 __attribute__((ext_vector_type(4)));

#define T_TOK 2048
#define HIDN  2048
#define NH    16
#define NKVH  4
#define HD    128
#define QKV_N 3072
#define NEXP  8
#define NPAIR_MAX 4608   // 4096 pairs + 8*63 padding, 64-aligned

#define MFMA16(a,b,c) __builtin_amdgcn_mfma_f32_16x16x32_f16(a,b,c,0,0,0)

__device__ __forceinline__ void gload_lds16(const half_t* g, half_t* l) {
    __builtin_amdgcn_global_load_lds(
        (const __attribute__((address_space(1))) void*)g,
        (__attribute__((address_space(3))) void*)l, 16, 0, 0);
}

__device__ __forceinline__ float silu_f(float g) {
    return g / (1.0f + expf(-g));
}

// ---------------------------------------------------------------------------
// rmsnorm over HIDN cols, write split f16
// ---------------------------------------------------------------------------
__global__ __launch_bounds__(256)
void rmsnorm_split_k(const float* __restrict__ x, const float* __restrict__ w,
                     half_t* __restrict__ hi, half_t* __restrict__ lo)
{
    const int row = blockIdx.x, tid = threadIdx.x;
    const float* xr = x + (size_t)row * HIDN;
    floatx4 v0 = *(const floatx4*)(xr + tid * 8);
    floatx4 v1 = *(const floatx4*)(xr + tid * 8 + 4);
    float ss = v0[0]*v0[0] + v0[1]*v0[1] + v0[2]*v0[2] + v0[3]*v0[3]
             + v1[0]*v1[0] + v1[1]*v1[1] + v1[2]*v1[2] + v1[3]*v1[3];
    for (int o = 32; o; o >>= 1) ss += __shfl_down(ss, o);
    __shared__ float red[4];
    if ((tid & 63) == 0) red[tid >> 6] = ss;
    __syncthreads();
    ss = red[0] + red[1] + red[2] + red[3];
    float rs = rsqrtf(ss * (1.0f / HIDN) + 1e-6f);
    floatx4 w0 = *(const floatx4*)(w + tid * 8);
    floatx4 w1 = *(const floatx4*)(w + tid * 8 + 4);
    float vv[8] = { v0[0]*w0[0], v0[1]*w0[1], v0[2]*w0[2], v0[3]*w0[3],
                    v1[0]*w1[0], v1[1]*w1[1], v1[2]*w1[2], v1[3]*w1[3] };
    half8 hv, lv;
#pragma unroll
    for (int j = 0; j < 8; ++j) {
        float o = vv[j] * rs;
        half_t h = (half_t)o;
        hv[j] = h;
        lv[j] = (half_t)((o - (float)h) * 1024.0f);
    }
    *(half8*)(hi + (size_t)row * HIDN + tid * 8) = hv;
    if (lo) *(half8*)(lo + (size_t)row * HIDN + tid * 8) = lv;
}

// ---------------------------------------------------------------------------
// Transpose fp32 -> split f16: dst[n][k] = src[k][n]. 32x32 tile.
// ---------------------------------------------------------------------------
__global__ __launch_bounds__(256)
void transpose_split2(const float* __restrict__ src,
                      half_t* __restrict__ dh, half_t* __restrict__ dl,
                      int sstride, int dstride)
{
    __shared__ float tile[32][36];
    const int n0 = blockIdx.x * 32, k0 = blockIdx.y * 32;
    const int tid = threadIdx.x;
    {
        int r = tid >> 3, c = (tid & 7) * 4;
        *(floatx4*)&tile[r][c] =
            *(const floatx4*)(src + (size_t)(k0 + r) * sstride + n0 + c);
    }
    __syncthreads();
    int n = tid & 31, g = tid >> 5, gg = g & 3;
    half8 hv;
    if (g < 4) {
#pragma unroll
        for (int j = 0; j < 8; ++j) hv[j] = (half_t)tile[gg * 8 + j][n];
        *(half8*)(dh + (size_t)(n0 + n) * dstride + k0 + gg * 8) = hv;
    } else {
#pragma unroll
        for (int j = 0; j < 8; ++j) {
            float v = tile[gg * 8 + j][n];
            half_t h = (half_t)v;
            hv[j] = (half_t)((v - (float)h) * 1024.0f);
        }
        *(half8*)(dl + (size_t)(n0 + n) * dstride + k0 + gg * 8) = hv;
    }
}

// ---------------------------------------------------------------------------
// Transpose fp32 -> single f16: dst[n][k] = src[k][n]. 32(k)x64(n) tile.
// ---------------------------------------------------------------------------
__global__ __launch_bounds__(256)
void transpose_f16(const float* __restrict__ src, half_t* __restrict__ dh,
                   int sstride, int dstride)
{
    __shared__ float tile[32][68];
    const int n0 = blockIdx.x * 64, k0 = blockIdx.y * 32;
    const int tid = threadIdx.x;
    {
        int r = tid >> 3, c = (tid & 7) * 4;
        const float* s = src + (size_t)(k0 + r) * sstride + n0;
        *(floatx4*)&tile[r][c]      = *(const floatx4*)(s + c);
        *(floatx4*)&tile[r][c + 32] = *(const floatx4*)(s + c + 32);
    }
    __syncthreads();
    int n = tid & 63, g = tid >> 6;
    half8 hv;
#pragma unroll
    for (int j = 0; j < 8; ++j) hv[j] = (half_t)tile[g * 8 + j][n];
    *(half8*)(dh + (size_t)(n0 + n) * dstride + k0 + g * 8) = hv;
}

// ---------------------------------------------------------------------------
// V^T transpose, single f16, SIGMA-PERMUTED within each 32-token block:
// vt[d][32m + s] = V[32m + sigma_inv(s)][d], sigma_inv(s) = (s&1)*16 + (s>>1).
// ---------------------------------------------------------------------------
__global__ __launch_bounds__(256)
void vt_transpose_perm(const float* __restrict__ src, half_t* __restrict__ dh)
{
    __shared__ float tile[32][68];
    const int n0 = blockIdx.x * 64, k0 = blockIdx.y * 32;
    const int tid = threadIdx.x;
    {
        int r = tid >> 3, c = (tid & 7) * 4;
        const float* s = src + (size_t)(k0 + r) * QKV_N + n0;
        *(floatx4*)&tile[r][c]      = *(const floatx4*)(s + c);
        *(floatx4*)&tile[r][c + 32] = *(const floatx4*)(s + c + 32);
    }
    __syncthreads();
    int n = tid & 63, g = tid >> 6;
    half8 hv;
#pragma unroll
    for (int tt = 0; tt < 8; ++tt) {
        int c_src = (tt & 1) * 16 + 4 * g + (tt >> 1);
        hv[tt] = (half_t)tile[c_src][n];
    }
    *(half8*)(dh + (size_t)(n0 + n) * T_TOK + k0 + g * 8) = hv;
}

// ---------------------------------------------------------------------------
// Batched W13 transpose: W13t[n][k], n<10240:
//  [0,1024): sw1 | [1024,2048): sw3 | [2048,6144): w1[e] | [6144,10240): w3[e]
// ---------------------------------------------------------------------------
__global__ __launch_bounds__(256)
void w13_transpose(const float* __restrict__ sw1, const float* __restrict__ w1,
                   const float* __restrict__ sw3, const float* __restrict__ w3,
                   half_t* __restrict__ dst)
{
    __shared__ float tile[32][68];
    const int n0 = blockIdx.x * 64, k0 = blockIdx.y * 32;
    const int tid = threadIdx.x;
    const float* base;
    int stride;
    if (n0 < 1024)      { base = sw1 + n0; stride = 1024; }
    else if (n0 < 2048) { base = sw3 + (n0 - 1024); stride = 1024; }
    else if (n0 < 6144) { int e = (n0 - 2048) >> 9;
                          base = w1 + (size_t)e * HIDN * 512 + ((n0 - 2048) & 511);
                          stride = 512; }
    else                { int e = (n0 - 6144) >> 9;
                          base = w3 + (size_t)e * HIDN * 512 + ((n0 - 6144) & 511);
                          stride = 512; }
    {
        int r = tid >> 3, c = (tid & 7) * 4;
        const float* s = base + (size_t)(k0 + r) * stride;
        *(floatx4*)&tile[r][c]      = *(const floatx4*)(s + c);
        *(floatx4*)&tile[r][c + 32] = *(const floatx4*)(s + c + 32);
    }
    __syncthreads();
    int n = tid & 63, g = tid >> 6;
    half8 hv;
#pragma unroll
    for (int j = 0; j < 8; ++j) hv[j] = (half_t)tile[g * 8 + j][n];
    *(half8*)(dst + (size_t)(n0 + n) * HIDN + k0 + g * 8) = hv;
}

// ---------------------------------------------------------------------------
// Batched W2 transpose: W2t[n][k] (n<2048, k<5120), f16, dstride 5120.
// ---------------------------------------------------------------------------
__global__ __launch_bounds__(256)
void w2_transpose(const float* __restrict__ sw2, const float* __restrict__ w2,
                  half_t* __restrict__ dst)
{
    __shared__ float tile[32][68];
    const int n0 = blockIdx.x * 64, k0 = blockIdx.y * 32;
    const int tid = threadIdx.x;
    {
        int r = tid >> 3, c = (tid & 7) * 4;
        int k = k0 + r;
        const float* s;
        if (k < 1024) s = sw2 + (size_t)k * HIDN + n0;
        else {
            int e = (k - 1024) >> 9, kk = (k - 1024) & 511;
            s = w2 + ((size_t)e * 512 + kk) * HIDN + n0;
        }
        *(floatx4*)&tile[r][c]      = *(const floatx4*)(s + c);
        *(floatx4*)&tile[r][c + 32] = *(const floatx4*)(s + c + 32);
    }
    __syncthreads();
    int n = tid & 63, g = tid >> 6;
    half8 hv;
#pragma unroll
    for (int j = 0; j < 8; ++j) hv[j] = (half_t)tile[g * 8 + j][n];
    *(half8*)(dst + (size_t)(n0 + n) * 5120 + k0 + g * 8) = hv;
}

// ---------------------------------------------------------------------------
// ow_u[k][e] = sum_c o_w[k][c]*ln2w[c]*rw[c][e]. Also folds MoE meta init.
// ---------------------------------------------------------------------------
__global__ __launch_bounds__(256)
void owu_kernel(const float* __restrict__ ow, const float* __restrict__ ln2w,
                const float* __restrict__ rw, float* __restrict__ owu,
                int* __restrict__ cnt, int* __restrict__ pairTok,
                float* __restrict__ pairW)
{
    if (blockIdx.x < 18) {
        int idx = blockIdx.x * 256 + threadIdx.x;
        if (idx < NPAIR_MAX) { pairTok[idx] = 0; pairW[idx] = 0.0f; }
        if (idx < NEXP) cnt[idx] = 0;
    }
    const int k = blockIdx.x * 4 + (threadIdx.x >> 6);
    const int lane = threadIdx.x & 63;
    float acc[NEXP] = {};
    const float* row = ow + (size_t)k * HIDN;
#pragma unroll
    for (int j = 0; j < 8; ++j) {
        int c = j * 256 + lane * 4;
        floatx4 ov = *(const floatx4*)(row + c);
        floatx4 lw = *(const floatx4*)(ln2w + c);
#pragma unroll
        for (int i = 0; i < 4; ++i) {
            float s = ov[i] * lw[i];
            const float* rwc = rw + (size_t)(c + i) * NEXP;
#pragma unroll
            for (int e = 0; e < NEXP; ++e) acc[e] += s * rwc[e];
        }
    }
#pragma unroll
    for (int e = 0; e < NEXP; ++e)
        for (int o = 32; o; o >>= 1) acc[e] += __shfl_down(acc[e], o);
    if (lane == 0) {
#pragma unroll
        for (int e = 0; e < NEXP; ++e) owu[(size_t)k * NEXP + e] = acc[e];
    }
}

// ---------------------------------------------------------------------------
// z moments -> f16, sigma-permuted, V^T-style layout.
// ---------------------------------------------------------------------------
__global__ __launch_bounds__(256)
void z_kernel(const float* __restrict__ qkv, const float* __restrict__ owu,
              half_t* __restrict__ zt)
{
    const int kv = blockIdx.x, tid = threadIdx.x;
    const int hh = tid >> 4, li = tid & 15;
    const float* vrow = qkv + (size_t)kv * QKV_N + 2560 + (hh >> 2) * HD;
    const int d0 = li * 8;
    float acc[NEXP] = {};
#pragma unroll
    for (int j = 0; j < 8; ++j) {
        float v = vrow[d0 + j];
        const float* ou = owu + (size_t)(hh * HD + d0 + j) * NEXP;
#pragma unroll
        for (int e = 0; e < NEXP; ++e) acc[e] += v * ou[e];
    }
#pragma unroll
    for (int e = 0; e < NEXP; ++e)
        for (int o = 1; o < 16; o <<= 1) acc[e] += __shfl_xor(acc[e], o);
    if (li == 0) {
        int j = kv & 31;
        int s = ((j & 15) << 1) | (j >> 4);
        size_t base = (size_t)(kv & ~31) + s;
#pragma unroll
        for (int e = 0; e < NEXP; ++e)
            zt[(size_t)(hh * 8 + e) * T_TOK + base] = (half_t)acc[e];
    }
}

// ---------------------------------------------------------------------------
// GEMM: C[M][N] = A[M][K] @ Bt[N][K]^T (+bias)(+res). f16 in, fp32 acc.
// SPLIT: (hi, lo*1024) pairs, 3 MFMAs/tile. BM x 128 tile, BK=32, 4 waves.
// ---------------------------------------------------------------------------
template<bool SPLIT, int BM>
__global__ __launch_bounds__(256, 2)
void gemm_f16(const half_t* __restrict__ Ah, const half_t* __restrict__ Al,
              const half_t* __restrict__ Bth, const half_t* __restrict__ Btl,
              const float* __restrict__ bias, const float* __restrict__ res,
              float* __restrict__ Cf, half_t* __restrict__ Ch,
              int M, int N, int K, int lda, int ldb)
{
    constexpr int NBUF = SPLIT ? 2 : 1;
    constexpr int MR = BM / 32;
    __shared__ half_t As[2][NBUF][BM * 32];
    __shared__ half_t Bs[2][NBUF][128 * 32];
    const int tid = threadIdx.x, lane = tid & 63, wid = tid >> 6;
    const int l15 = lane & 15, l4 = lane >> 4;
    const int row0 = blockIdx.y * BM, col0 = blockIdx.x * 128;
    const int wr = (wid >> 1) * (BM / 2), wc = (wid & 1) * 64;
    f32x4 accM[MR][4] = {}, accC[MR][4] = {};
    const int lrw = lane >> 2, lcl = (lane & 3) * 8;

#define STAGE(BUF, K0)                                                        \
    do {                                                                      \
        _Pragma("unroll")                                                     \
        for (int j = 0; j < BM / 64; ++j) {                                   \
            const int r = wid * (BM / 4) + j * 16;                            \
            const size_t ga = (size_t)(row0 + r + lrw) * lda + (K0) + lcl;    \
            gload_lds16(Ah + ga, &As[BUF][0][r * 32]);                        \
            if constexpr (SPLIT) gload_lds16(Al + ga, &As[BUF][1][r * 32]);   \
        }                                                                     \
        _Pragma("unroll")                                                     \
        for (int j = 0; j < 2; ++j) {                                         \
            const int r = wid * 32 + j * 16;                                  \
            const size_t gb = (size_t)(col0 + r + lrw) * ldb + (K0) + lcl;    \
            gload_lds16(Bth + gb, &Bs[BUF][0][r * 32]);                       \
            if constexpr (SPLIT) gload_lds16(Btl + gb, &Bs[BUF][1][r * 32]);  \
        }                                                                     \
    } while (0)

    STAGE(0, 0);
    __syncthreads();
    int cur = 0;
    for (int k0 = 0; k0 < K; k0 += 32, cur ^= 1) {
        if (k0 + 32 < K) STAGE(cur ^ 1, k0 + 32);
        half8 ah[MR], al[MR], bh[4], bl[4];
#pragma unroll
        for (int m = 0; m < MR; ++m) {
            int off = (wr + m * 16 + l15) * 32 + l4 * 8;
            ah[m] = *(const half8*)&As[cur][0][off];
            if constexpr (SPLIT) al[m] = *(const half8*)&As[cur][1][off];
        }
#pragma unroll
        for (int n = 0; n < 4; ++n) {
            int off = (wc + n * 16 + l15) * 32 + l4 * 8;
            bh[n] = *(const half8*)&Bs[cur][0][off];
            if constexpr (SPLIT) bl[n] = *(const half8*)&Bs[cur][1][off];
        }
#pragma unroll
        for (int m = 0; m < MR; ++m)
#pragma unroll
            for (int n = 0; n < 4; ++n) {
                accM[m][n] = MFMA16(ah[m], bh[n], accM[m][n]);
                if constexpr (SPLIT) {
                    accC[m][n] = MFMA16(ah[m], bl[n], accC[m][n]);
                    accC[m][n] = MFMA16(al[m], bh[n], accC[m][n]);
                }
            }
        __syncthreads();
    }
#undef STAGE

#pragma unroll
    for (int m = 0; m < MR; ++m) {
#pragma unroll
        for (int n = 0; n < 4; ++n) {
            int gr0 = row0 + wr + m * 16 + l4 * 4;
            int gc  = col0 + wc + n * 16 + l15;
            float b = bias ? bias[gc] : 0.0f;
#pragma unroll
            for (int i = 0; i < 4; ++i) {
                float v = accM[m][n][i];
                if constexpr (SPLIT) v += accC[m][n][i] * (1.0f / 1024.0f);
                v += b;
                size_t idx = (size_t)(gr0 + i) * N + gc;
                if (res) v += res[idx];
                if (Cf) Cf[idx] = v;
                if (Ch) Ch[idx] = (half_t)v;
            }
        }
    }
}

// ---------------------------------------------------------------------------
// Unified fused GU GEMM + silu act: one launch, 1088 blocks (BM=64).
// ex[] aliased onto As/Bs via union -- LDS 41.4 -> 24KB (R17).
// Safe: the final K-iteration ends with __syncthreads (all As/Bs reads and
// in-flight gload_lds drained) before ex is first written.
// ---------------------------------------------------------------------------
__global__ __launch_bounds__(256, 2)
void gemm_gu_all(const half_t* __restrict__ h2, const half_t* __restrict__ W13t,
                 const int* __restrict__ pairTok, const int* __restrict__ basep,
                 const float* __restrict__ pairW,
                 half_t* __restrict__ As_out, half_t* __restrict__ Ab_out)
{
    __shared__ union SM {
        struct { half_t As[2][64 * 32]; half_t Bs[2][128 * 32]; } s;  // 24KB
        half_t ex[64][136];                                           // 17.4KB
    } sm;
    const int bid = blockIdx.x;
    const bool grouped = (bid >= 512);
    int ct, row0;
    if (!grouped) { ct = bid & 15;          row0 = (bid >> 4) * 64; }
    else          { int g = bid - 512; ct = g & 7; row0 = (g >> 3) * 64; }
    const int tid = threadIdx.x, lane = tid & 63, wid = tid >> 6;
    const int l15 = lane & 15, l4 = lane >> 4;
    const int lrw = lane >> 2, lcl = (lane & 3) * 8;
    int gbase, ubase;
    if (grouped) {
        int e = 0;
#pragma unroll
        for (int i = 1; i < NEXP; ++i) if (row0 >= basep[i]) e = i;
        gbase = 2048 + 512 * e + ct * 64;
        ubase = 6144 + 512 * e + ct * 64;
    } else {
        gbase = ct * 64;
        ubase = 1024 + ct * 64;
    }
    const int wr = (wid >> 1) * 32, wc = (wid & 1) * 64;
    const half_t* Abase;
    if (grouped) {
        const int tok = pairTok[row0 + wid * 16 + lrw];
        Abase = h2 + (size_t)tok * HIDN + lcl;
    } else {
        Abase = h2 + (size_t)(row0 + wid * 16 + lrw) * HIDN + lcl;
    }
    f32x4 acc[2][4] = {};

#define GSTAGE(BUF, K0)                                                       \
    do {                                                                      \
        gload_lds16(Abase + (K0), &sm.s.As[BUF][(wid * 16) * 32]);            \
        _Pragma("unroll")                                                     \
        for (int j = 0; j < 2; ++j) {                                         \
            const int r = wid * 32 + j * 16;                                  \
            const int grow = (r < 64) ? gbase + r : ubase + (r - 64);         \
            const size_t gb = (size_t)(grow + lrw) * HIDN + (K0) + lcl;       \
            gload_lds16(W13t + gb, &sm.s.Bs[BUF][r * 32]);                    \
        }                                                                     \
    } while (0)

    GSTAGE(0, 0);
    __syncthreads();
    int cur = 0;
    for (int k0 = 0; k0 < HIDN; k0 += 32, cur ^= 1) {
        if (k0 + 32 < HIDN) GSTAGE(cur ^ 1, k0 + 32);
        half8 ah[2], bh[4];
#pragma unroll
        for (int m = 0; m < 2; ++m)
            ah[m] = *(const half8*)&sm.s.As[cur][(wr + m * 16 + l15) * 32 + l4 * 8];
#pragma unroll
        for (int n = 0; n < 4; ++n)
            bh[n] = *(const half8*)&sm.s.Bs[cur][(wc + n * 16 + l15) * 32 + l4 * 8];
#pragma unroll
        for (int m = 0; m < 2; ++m)
#pragma unroll
            for (int n = 0; n < 4; ++n)
                acc[m][n] = MFMA16(ah[m], bh[n], acc[m][n]);
        __syncthreads();
    }
#undef GSTAGE

    // epilogue: As/Bs fully drained by the last barrier -> reuse as ex
#pragma unroll
    for (int m = 0; m < 2; ++m)
#pragma unroll
        for (int n = 0; n < 4; ++n)
#pragma unroll
            for (int i = 0; i < 4; ++i)
                sm.ex[wr + m * 16 + l4 * 4 + i][wc + n * 16 + l15] =
                    (half_t)acc[m][n][i];
    __syncthreads();
    const int OSTR = grouped ? 512 : 1024;
    half_t* outp = grouped ? Ab_out : As_out;
#pragma unroll
    for (int w2 = 0; w2 < 2; ++w2) {
        int unit = tid * 2 + w2;
        int row = unit >> 3, cgx = (unit & 7) * 8;
        half8 g8 = *(const half8*)&sm.ex[row][cgx];
        half8 u8 = *(const half8*)&sm.ex[row][64 + cgx];
        float wgt = grouped ? pairW[row0 + row] : 1.0f;
        half8 o8;
#pragma unroll
        for (int j = 0; j < 8; ++j)
            o8[j] = (half_t)(silu_f((float)g8[j]) * (float)u8[j] * wgt);
        *(half8*)(outp + (size_t)(row0 + row) * OSTR + ct * 64 + cgx) = o8;
    }
}

// ---------------------------------------------------------------------------
// Fused down GEMM: grid (16, 104). by<32: shared (out = x2 + ...); else
// grouped (Ypair). BM=64 (R15).
// ---------------------------------------------------------------------------
__global__ __launch_bounds__(256, 2)
void gemm_down_all(const half_t* __restrict__ As_sh, const half_t* __restrict__ Ab,
                   const half_t* __restrict__ W2t, const int* __restrict__ basep,
                   const float* __restrict__ x2, float* __restrict__ out,
                   half_t* __restrict__ Ypair)
{
    __shared__ half_t Asm[2][64 * 32];
    __shared__ half_t Bsm[2][128 * 32];
    const int tid = threadIdx.x, lane = tid & 63, wid = tid >> 6;
    const int l15 = lane & 15, l4 = lane >> 4;
    const int lrw = lane >> 2, lcl = (lane & 3) * 8;
    const int col0 = blockIdx.x * 128;
    const bool shared = (blockIdx.y < 32);
    const int row0 = (shared ? blockIdx.y : blockIdx.y - 32) * 64;
    const half_t* A;
    int lda, K, bcol;
    if (shared) { A = As_sh; lda = 1024; K = 1024; bcol = 0; }
    else {
        int e = 0;
#pragma unroll
        for (int i = 1; i < NEXP; ++i) if (row0 >= basep[i]) e = i;
        A = Ab; lda = 512; K = 512; bcol = 1024 + 512 * e;
    }
    const int wr = (wid >> 1) * 32, wc = (wid & 1) * 64;
    f32x4 acc[2][4] = {};

#define DSTAGE(BUF, K0)                                                       \
    do {                                                                      \
        const size_t ga = (size_t)(row0 + wid * 16 + lrw) * lda + (K0) + lcl; \
        gload_lds16(A + ga, &Asm[BUF][(wid * 16) * 32]);                      \
        _Pragma("unroll")                                                     \
        for (int j = 0; j < 2; ++j) {                                         \
            const int r = wid * 32 + j * 16;                                  \
            const size_t gb = (size_t)(col0 + r + lrw) * 5120 + bcol + (K0) + lcl; \
            gload_lds16(W2t + gb, &Bsm[BUF][r * 32]);                         \
        }                                                                     \
    } while (0)

    DSTAGE(0, 0);
    __syncthreads();
    int cur = 0;
    for (int k0 = 0; k0 < K; k0 += 32, cur ^= 1) {
        if (k0 + 32 < K) DSTAGE(cur ^ 1, k0 + 32);
        half8 ah[2], bh[4];
#pragma unroll
        for (int m = 0; m < 2; ++m)
            ah[m] = *(const half8*)&Asm[cur][(wr + m * 16 + l15) * 32 + l4 * 8];
#pragma unroll
        for (int n = 0; n < 4; ++n)
            bh[n] = *(const half8*)&Bsm[cur][(wc + n * 16 + l15) * 32 + l4 * 8];
#pragma unroll
        for (int m = 0; m < 2; ++m)
#pragma unroll
            for (int n = 0; n < 4; ++n)
                acc[m][n] = MFMA16(ah[m], bh[n], acc[m][n]);
        __syncthreads();
    }
#undef DSTAGE

#pragma unroll
    for (int m = 0; m < 2; ++m)
#pragma unroll
        for (int n = 0; n < 4; ++n) {
            int gr0 = row0 + wr + m * 16 + l4 * 4;
            int gc  = col0 + wc + n * 16 + l15;
#pragma unroll
            for (int i = 0; i < 4; ++i) {
                size_t idx = (size_t)(gr0 + i) * HIDN + gc;
                if (shared) out[idx] = x2[idx] + acc[m][n][i];
                else        Ypair[idx] = (half_t)acc[m][n][i];
            }
        }
}

// ---------------------------------------------------------------------------
// qkv post-processing: k-rmsnorm, RoPE on q/k, Q pre-scaled, split-f16 out.
// ---------------------------------------------------------------------------
__global__ __launch_bounds__(256)
void qkv_prep(const float* __restrict__ qkv, const int* __restrict__ pos,
              const float* __restrict__ klnw,
              half_t* __restrict__ qh, half_t* __restrict__ ql,
              half_t* __restrict__ kh, half_t* __restrict__ kl)
{
    const int t = blockIdx.x, tid = threadIdx.x, lane = tid & 63, wid = tid >> 6;
    const float* row = qkv + (size_t)t * QKV_N;
    __shared__ float cs[32], sn[32];
    if (tid < 32) {
        double freq = exp((double)tid * -0.28782313662425572);  // -ln(1e4)/32
        double ang = (double)pos[t] * freq;
        const double twopi = 6.283185307179586476925286766559;
        ang -= twopi * floor(ang * (1.0 / twopi));
        float a = (float)ang;
        cs[tid] = cosf(a);
        sn[tid] = sinf(a);
    }
    __syncthreads();

    const float qscale = 0.08838834764831845f;   // 128^-0.5
    {
        const int hh = tid >> 4, d0 = (tid & 15) * 8;
        const float* qrow = row + hh * HD;
        float outv[8];
        if (d0 < 64) {
#pragma unroll
            for (int j = 0; j < 8; ++j) outv[j] = qrow[d0 + j];
        } else if (d0 < 96) {
            int j0 = d0 - 64;
#pragma unroll
            for (int j = 0; j < 8; ++j) {
                int jj = j0 + j;
                outv[j] = qrow[64 + jj] * cs[jj] - qrow[96 + jj] * sn[jj];
            }
        } else {
            int j0 = d0 - 96;
#pragma unroll
            for (int j = 0; j < 8; ++j) {
                int jj = j0 + j;
                outv[j] = qrow[64 + jj] * sn[jj] + qrow[96 + jj] * cs[jj];
            }
        }
        half8 hv, lv;
#pragma unroll
        for (int j = 0; j < 8; ++j) {
            float o = outv[j] * qscale;
            half_t h = (half_t)o;
            hv[j] = h;
            lv[j] = (half_t)((o - (float)h) * 1024.0f);
        }
        size_t base = (size_t)t * (NH * HD) + hh * HD + d0;
        *(half8*)(qh + base) = hv;
        *(half8*)(ql + base) = lv;
    }
    {
        const float* krow = row + NH * HD + wid * HD;
        float a0 = krow[lane], a1 = krow[64 + lane];
        float ss = a0 * a0 + a1 * a1;
        for (int o = 32; o; o >>= 1) ss += __shfl_down(ss, o);
        ss = __shfl(ss, 0);
        float rs = rsqrtf(ss * (1.0f / HD) + 1e-6f);
        float n0 = a0 * rs * klnw[lane];
        float n1 = a1 * rs * klnw[64 + lane];
        float other = __shfl_xor(n1, 32);
        int j = lane & 31;
        float o1 = (lane < 32) ? (n1 * cs[j] - other * sn[j])
                               : (other * sn[j] + n1 * cs[j]);
        size_t base = (size_t)t * (NKVH * HD) + wid * HD;
        half_t h;
        h = (half_t)n0; kh[base + lane] = h;
        kl[base + lane] = (half_t)((n0 - (float)h) * 1024.0f);
        h = (half_t)o1; kh[base + 64 + lane] = h;
        kl[base + 64 + lane] = (half_t)((o1 - (float)h) * 1024.0f);
    }
}

// ---------------------------------------------------------------------------
// Chunked flash attention, causal GQA, KVBLK=64. QK^T split-f16; PV single-
// f16 with sigma-permuted V. z-moments ride the PV MFMA (Vsh rows 128-135);
// om[8] accumulates zacc; rows 136-143 unstaged garbage, outputs unread.
// ---------------------------------------------------------------------------
__global__ __launch_bounds__(256, 2)
void attn_kernel(const half_t* __restrict__ qh, const half_t* __restrict__ ql,
                 const half_t* __restrict__ kh, const half_t* __restrict__ kl,
                 const half_t* __restrict__ vth, const half_t* __restrict__ zt,
                 half_t* __restrict__ oh,
                 float* __restrict__ Op0, float* __restrict__ Op1,
                 float* __restrict__ Op2, float* __restrict__ ml,
                 float* __restrict__ zpart, float* __restrict__ zfin)
{
    const int bid = blockIdx.x;
    const int h = bid & 15;
    int rrem = bid >> 4, q = 31, nch = 6, c = 0;
    for (; q >= 0; --q) {
        nch = (q + 6) / 6;
        if (rrem < nch) { c = rrem; break; }
        rrem -= nch;
    }
    const int nt = q + 1;                        // 64-wide kv tiles
    const int kvbeg = ((c * nt) / nch) * 64;
    const int kvend = (((c + 1) * nt) / nch) * 64;

    const int kvh = h >> 2;
    const int tid = threadIdx.x, lane = tid & 63, wid = tid >> 6;
    const int q0 = q * 64 + wid * 16;
    const int l15 = lane & 15, l4 = lane >> 4;

    __shared__ half_t Ksh[64][136], Ksl[64][136];
    __shared__ half_t Vsh[144][72];              // rows 128-135: z (f16)
    __shared__ half_t Ph[4][16][72];

    half8 qfh[4], qfl[4];
    {
        const size_t qb = (size_t)(q0 + l15) * (NH * HD) + h * HD + l4 * 8;
#pragma unroll
        for (int cc = 0; cc < 4; ++cc) {
            qfh[cc] = *(const half8*)(qh + qb + cc * 32);
            qfl[cc] = *(const half8*)(ql + qb + cc * 32);
        }
    }

    f32x4 om[9] = {};                            // om[8] = z accumulator
    float mrow[4] = { -1e30f, -1e30f, -1e30f, -1e30f };
    float lrow[4] = {};

    const int kr = tid >> 2, kc0 = (tid & 3) * 32;
    const int vd = tid >> 1, vc0 = (tid & 1) * 32;
    const int ze = tid >> 5, zc0 = (tid & 31) * 2;
    uint4 rkh0, rkh1, rkh2, rkh3, rkl0, rkl1, rkl2, rkl3;
    uint4 rv0, rv1, rv2, rv3;
    unsigned rzw;

#define LOAD_TILE(KV0)                                                        \
    do {                                                                      \
        size_t sk = (size_t)((KV0) + kr) * (NKVH * HD) + kvh * HD + kc0;      \
        rkh0 = *(const uint4*)(kh + sk);       rkl0 = *(const uint4*)(kl + sk);      \
        rkh1 = *(const uint4*)(kh + sk + 8);   rkl1 = *(const uint4*)(kl + sk + 8);  \
        rkh2 = *(const uint4*)(kh + sk + 16);  rkl2 = *(const uint4*)(kl + sk + 16); \
        rkh3 = *(const uint4*)(kh + sk + 24);  rkl3 = *(const uint4*)(kl + sk + 24); \
        size_t sv = (size_t)(kvh * HD + vd) * T_TOK + (KV0) + vc0;            \
        rv0 = *(const uint4*)(vth + sv);       rv1 = *(const uint4*)(vth + sv + 8);  \
        rv2 = *(const uint4*)(vth + sv + 16);  rv3 = *(const uint4*)(vth + sv + 24); \
        rzw = *(const unsigned*)(zt + (size_t)(h * 8 + ze) * T_TOK + (KV0) + zc0);   \
    } while (0)

    LOAD_TILE(kvbeg);
    for (int kv0 = kvbeg; kv0 < kvend; kv0 += 64) {
        *(uint4*)&Ksh[kr][kc0]      = rkh0;  *(uint4*)&Ksl[kr][kc0]      = rkl0;
        *(uint4*)&Ksh[kr][kc0 + 8]  = rkh1;  *(uint4*)&Ksl[kr][kc0 + 8]  = rkl1;
        *(uint4*)&Ksh[kr][kc0 + 16] = rkh2;  *(uint4*)&Ksl[kr][kc0 + 16] = rkl2;
        *(uint4*)&Ksh[kr][kc0 + 24] = rkh3;  *(uint4*)&Ksl[kr][kc0 + 24] = rkl3;
        *(uint4*)&Vsh[vd][vc0]      = rv0;   *(uint4*)&Vsh[vd][vc0 + 8]  = rv1;
        *(uint4*)&Vsh[vd][vc0 + 16] = rv2;   *(uint4*)&Vsh[vd][vc0 + 24] = rv3;
        *(unsigned*)&Vsh[128 + ze][zc0] = rzw;
        __syncthreads();
        if (kv0 + 64 < kvend) LOAD_TILE(kv0 + 64);   // hides under compute

        f32x4 sf[4];
        __builtin_amdgcn_s_setprio(1);
#pragma unroll
        for (int t2 = 0; t2 < 4; ++t2) {       // S = Q K^T (pre-scaled Q)
            f32x4 s = {}, sc1 = {}, sc2 = {};
#pragma unroll
            for (int cc = 0; cc < 4; ++cc) {
                half8 bh = *(const half8*)&Ksh[t2 * 16 + l15][cc * 32 + l4 * 8];
                half8 bl = *(const half8*)&Ksl[t2 * 16 + l15][cc * 32 + l4 * 8];
                s   = MFMA16(qfh[cc], bh, s);
                sc1 = MFMA16(qfh[cc], bl, sc1);
                sc2 = MFMA16(qfl[cc], bh, sc2);
            }
            sf[t2] = s + (sc1 + sc2) * (1.0f / 1024.0f);
        }
        __builtin_amdgcn_s_setprio(0);

        float pmax[4];
#pragma unroll
        for (int i = 0; i < 4; ++i) {
            const int qg = q0 + l4 * 4 + i;
#pragma unroll
            for (int t2 = 0; t2 < 4; ++t2) {
                int kvg = kv0 + t2 * 16 + l15;
                if (kvg > qg) sf[t2][i] = -1e30f;
            }
            float mx = fmaxf(fmaxf(sf[0][i], sf[1][i]),
                             fmaxf(sf[2][i], sf[3][i]));
#pragma unroll
            for (int o = 1; o < 16; o <<= 1) mx = fmaxf(mx, __shfl_xor(mx, o));
            pmax[i] = mx;
        }
        float dm = fmaxf(fmaxf(pmax[0] - mrow[0], pmax[1] - mrow[1]),
                         fmaxf(pmax[2] - mrow[2], pmax[3] - mrow[3]));
        if (__any(dm > 6.0f)) {                // defer-max
#pragma unroll
            for (int i = 0; i < 4; ++i) {
                float mnew = fmaxf(mrow[i], pmax[i]);
                float resc = expf(mrow[i] - mnew);
                lrow[i] *= resc;
#pragma unroll
                for (int c8 = 0; c8 < 9; ++c8) om[c8][i] *= resc;
                mrow[i] = mnew;
            }
        }
#pragma unroll
        for (int i = 0; i < 4; ++i) {
            float p0 = expf(sf[0][i] - mrow[i]);
            float p1 = expf(sf[1][i] - mrow[i]);
            float p2 = expf(sf[2][i] - mrow[i]);
            float p3 = expf(sf[3][i] - mrow[i]);
            lrow[i] += (p0 + p1) + (p2 + p3);
            half2v ppA = { (half_t)p0, (half_t)p1 };   // sigma-interleaved
            half2v ppB = { (half_t)p2, (half_t)p3 };
            *(half2v*)&Ph[wid][l4 * 4 + i][l15 * 2]      = ppA;
            *(half2v*)&Ph[wid][l4 * 4 + i][32 + l15 * 2] = ppB;
        }

        half8 pa0 = *(const half8*)&Ph[wid][l15][l4 * 8];
        half8 pa1 = *(const half8*)&Ph[wid][l15][32 + l4 * 8];
        __builtin_amdgcn_s_setprio(1);
#pragma unroll
        for (int c8 = 0; c8 < 9; ++c8) {       // O += P V ; om[8] += P z
            half8 v0 = *(const half8*)&Vsh[c8 * 16 + l15][l4 * 8];
            half8 v1 = *(const half8*)&Vsh[c8 * 16 + l15][32 + l4 * 8];
            om[c8] = MFMA16(pa0, v0, om[c8]);
            om[c8] = MFMA16(pa1, v1, om[c8]);
        }
        __builtin_amdgcn_s_setprio(0);
        __syncthreads();
    }
#undef LOAD_TILE

#pragma unroll
    for (int i = 0; i < 4; ++i)
#pragma unroll
        for (int o = 1; o < 16; o <<= 1) lrow[i] += __shfl_xor(lrow[i], o);

    if (l15 < 8) {
        const int e = l15;
#pragma unroll
        for (int i = 0; i < 4; ++i) {
            int row64 = wid * 16 + l4 * 4 + i;
            if (nch == 1) {
                zfin[((size_t)(q * 64 + row64) * 16 + h) * 8 + e] =
                    om[8][i] / lrow[i];
            } else {
                zpart[((size_t)bid * 64 + row64) * 8 + e] = om[8][i];
            }
        }
    }

    if (nch == 1) {
#pragma unroll
        for (int c8 = 0; c8 < 8; ++c8) {
#pragma unroll
            for (int i = 0; i < 4; ++i) {
                float v = om[c8][i] / lrow[i];
                size_t idx = (size_t)(q0 + l4 * 4 + i) * (NH * HD) + h * HD
                           + c8 * 16 + l15;
                oh[idx] = (half_t)v;
            }
        }
    } else {
        float* Op = (bid < 768)  ? Op0 + (size_t)bid * 8192
                  : (bid < 1280) ? Op1 + (size_t)(bid - 768) * 8192
                                 : Op2 + (size_t)(bid - 1280) * 8192;
#pragma unroll
        for (int c8 = 0; c8 < 8; ++c8) {
#pragma unroll
            for (int i = 0; i < 4; ++i) {
                int row64 = wid * 16 + l4 * 4 + i;
                Op[row64 * 128 + c8 * 16 + l15] = om[c8][i];
            }
        }
        if (l15 == 0) {
#pragma unroll
            for (int i = 0; i < 4; ++i) {
                int row64 = wid * 16 + l4 * 4 + i;
                ml[(size_t)bid * 128 + row64]      = mrow[i];
                ml[(size_t)bid * 128 + 64 + row64] = lrow[i];
            }
        }
    }
}

// ---------------------------------------------------------------------------
// Combine partial attention chunks (q >= 6): O merge + z-moment merge.
// ---------------------------------------------------------------------------
__device__ __forceinline__ const float* slot_ptr(int s, const float* Op0,
                                                 const float* Op1,
                                                 const float* Op2)
{
    return (s < 768)  ? Op0 + (size_t)s * 8192
         : (s < 1280) ? Op1 + (size_t)(s - 768) * 8192
                      : Op2 + (size_t)(s - 1280) * 8192;
}

__global__ __launch_bounds__(256)
void attn_combine(const float* __restrict__ Op0, const float* __restrict__ Op1,
                  const float* __restrict__ Op2, const float* __restrict__ ml,
                  const float* __restrict__ zpart,
                  half_t* __restrict__ oh, float* __restrict__ zfin)
{
    const int bid = blockIdx.x;
    const int h = bid & 15, q = 6 + (bid >> 4);
    const int nch = (q + 6) / 6;
    int r0 = 0;
    for (int j = 31; j > q; --j) r0 += (j + 6) / 6;
    const int tid = threadIdx.x;
    const int row = tid >> 2, cg = (tid & 3) * 32;

    float M = -1e30f;
    for (int c = 0; c < nch; ++c) {
        int s = (r0 + c) * 16 + h;
        M = fmaxf(M, ml[(size_t)s * 128 + row]);
    }
    float wsum = 0.0f;
    for (int c = 0; c < nch; ++c) {
        int s = (r0 + c) * 16 + h;
        wsum += ml[(size_t)s * 128 + 64 + row] *
                expf(ml[(size_t)s * 128 + row] - M);
    }
    float inv = 1.0f / wsum;

    if ((tid & 3) == 0) {
        f32x4 a = {0,0,0,0}, b = {0,0,0,0};
        for (int c = 0; c < nch; ++c) {
            int s = (r0 + c) * 16 + h;
            float w = expf(ml[(size_t)s * 128 + row] - M) * inv;
            size_t zo = ((size_t)s * 64 + row) * 8;
            a += w * (*(const f32x4*)&zpart[zo]);
            b += w * (*(const f32x4*)&zpart[zo + 4]);
        }
        size_t zo = ((size_t)(q * 64 + row) * 16 + h) * 8;
        *(f32x4*)&zfin[zo]     = a;
        *(f32x4*)&zfin[zo + 4] = b;
    }

    size_t obase = (size_t)(q * 64 + row) * (NH * HD) + h * HD + cg;
#pragma unroll
    for (int jj = 0; jj < 4; ++jj) {
        floatx4 a0 = {0,0,0,0}, a1 = {0,0,0,0};
        for (int c = 0; c < nch; ++c) {
            int s = (r0 + c) * 16 + h;
            float w = expf(ml[(size_t)s * 128 + row] - M) * inv;
            const float* base = slot_ptr(s, Op0, Op1, Op2) + row * 128 + cg;
            a0 += w * (*(const floatx4*)(base + jj * 8));
            a1 += w * (*(const floatx4*)(base + jj * 8 + 4));
        }
        half8 hv;
#pragma unroll
        for (int k = 0; k < 4; ++k) {
            hv[k]     = (half_t)a0[k];
            hv[4 + k] = (half_t)a1[k];
        }
        *(half8*)(oh + obase + jj * 8) = hv;
    }
}

// ---------------------------------------------------------------------------
// Linear router: logit_e = rs(x2)*(x.u_e + sum_h zfin[t][h][e]).
// Writes top-2 + histogram + h2 = rmsnorm(x2, ln2w).
// ---------------------------------------------------------------------------
__global__ __launch_bounds__(256)
void router_linear(const float* __restrict__ x, const float* __restrict__ zfin,
                   const float* __restrict__ x2,
                   const float* __restrict__ ln2w, const float* __restrict__ rw,
                   int* __restrict__ topi, float* __restrict__ topv,
                   int* __restrict__ cnt, half_t* __restrict__ h2)
{
    const int t = blockIdx.x, tid = threadIdx.x;
    const float* xr2 = x2 + (size_t)t * HIDN + tid * 8;
    floatx4 x2a = *(const floatx4*)(xr2);
    floatx4 x2b = *(const floatx4*)(xr2 + 4);
    float ss = x2a[0]*x2a[0] + x2a[1]*x2a[1] + x2a[2]*x2a[2] + x2a[3]*x2a[3]
             + x2b[0]*x2b[0] + x2b[1]*x2b[1] + x2b[2]*x2b[2] + x2b[3]*x2b[3];
    for (int o = 32; o; o >>= 1) ss += __shfl_down(ss, o);
    __shared__ float red[4];
    if ((tid & 63) == 0) red[tid >> 6] = ss;
    __syncthreads();
    ss = red[0] + red[1] + red[2] + red[3];
    float rs = rsqrtf(ss * (1.0f / HIDN) + 1e-6f);

    const float* xr = x + (size_t)t * HIDN + tid * 8;
    floatx4 xa = *(const floatx4*)(xr);
    floatx4 xb = *(const floatx4*)(xr + 4);
    floatx4 lwa = *(const floatx4*)(ln2w + tid * 8);
    floatx4 lwb = *(const floatx4*)(ln2w + tid * 8 + 4);

    float acc[NEXP] = {};
#pragma unroll
    for (int j = 0; j < 8; ++j) {
        int c = tid * 8 + j;
        float xv = (j < 4 ? xa[j] : xb[j - 4]) * (j < 4 ? lwa[j] : lwb[j - 4]);
        const float* rwc = rw + (size_t)c * NEXP;
#pragma unroll
        for (int e = 0; e < NEXP; ++e) acc[e] += xv * rwc[e];
    }
#pragma unroll
    for (int e = 0; e < NEXP; ++e)
        for (int o = 32; o; o >>= 1) acc[e] += __shfl_down(acc[e], o);
    __shared__ float red8[4][NEXP];
    if ((tid & 63) == 0)
#pragma unroll
        for (int e = 0; e < NEXP; ++e) red8[tid >> 6][e] = acc[e];

    __shared__ float zred[NEXP * 16];
    if (tid < 128) {
        int hh = tid >> 3, e = tid & 7;
        zred[e * 16 + hh] = zfin[((size_t)t * 16 + hh) * 8 + e];
    }

    half8 h2v;
#pragma unroll
    for (int j = 0; j < 8; ++j) {
        float xv = (j < 4 ? x2a[j] : x2b[j - 4]) * (j < 4 ? lwa[j] : lwb[j - 4]);
        h2v[j] = (half_t)(xv * rs);
    }
    *(half8*)(h2 + (size_t)t * HIDN + tid * 8) = h2v;

    __syncthreads();
    if (tid == 0) {
        float lg[NEXP];
#pragma unroll
        for (int e = 0; e < NEXP; ++e) {
            float zs = 0.0f;
#pragma unroll
            for (int hh = 0; hh < 16; ++hh) zs += zred[e * 16 + hh];
            lg[e] = (red8[0][e] + red8[1][e] + red8[2][e] + red8[3][e] + zs) * rs;
        }
        int i1 = 0;
        for (int e = 1; e < NEXP; ++e) if (lg[e] > lg[i1]) i1 = e;
        int i2 = (i1 == 0) ? 1 : 0;
        for (int e = 0; e < NEXP; ++e) if (e != i1 && lg[e] > lg[i2]) i2 = e;
        float mx = lg[i1];
        float p1 = expf(lg[i1] - mx), p2 = expf(lg[i2] - mx);
        float inv = 1.0f / (p1 + p2);
        topi[2 * t] = i1;       topi[2 * t + 1] = i2;
        topv[2 * t] = p1 * inv; topv[2 * t + 1] = p2 * inv;
        atomicAdd(&cnt[i1], 1);
        atomicAdd(&cnt[i2], 1);
    }
}

// ---------------------------------------------------------------------------
// Deterministic pair-list build (ballot prefix scan), 64-aligned regions.
// ---------------------------------------------------------------------------
__global__ __launch_bounds__(256)
void moe_build(const int* __restrict__ cnt, int* __restrict__ basep,
               const int* __restrict__ topi, const float* __restrict__ topv,
               int* __restrict__ pairTok, float* __restrict__ pairW,
               int* __restrict__ pairPos)
{
    const int e = blockIdx.x;
    int base = 0;
    for (int i = 0; i < e; ++i) base += (cnt[i] + 63) & ~63;
    if (threadIdx.x == 0) basep[e] = base;

    const int tid = threadIdx.x, lane = tid & 63, wv = tid >> 6;
    __shared__ int wsum[4];
    int run = base;
    for (int i0 = 0; i0 < 2 * T_TOK; i0 += 256) {
        int i = i0 + tid;
        bool m = (topi[i] == e);
        unsigned long long bal = __ballot(m);
        int lpre = __popcll(bal & ((1ull << lane) - 1ull));
        if (lane == 0) wsum[wv] = (int)__popcll(bal);
        __syncthreads();
        int woff = 0;
        for (int w = 0; w < wv; ++w) woff += wsum[w];
        if (m) {
            int pos = run + woff + lpre;
            pairTok[pos] = i >> 1;
            pairW[pos]   = topv[i];
            pairPos[i]   = pos;
        }
        run += wsum[0] + wsum[1] + wsum[2] + wsum[3];
        __syncthreads();
    }
}

// ---------------------------------------------------------------------------
// Final: out[t] += Ypair[p1] + Ypair[p2]
// ---------------------------------------------------------------------------
__global__ __launch_bounds__(256)
void moe_final(const half_t* __restrict__ Ypair, const int* __restrict__ pairPos,
               float* __restrict__ out)
{
    int t = blockIdx.x, c0 = threadIdx.x * 8;
    int p1 = pairPos[2 * t], p2 = pairPos[2 * t + 1];
    half8 y1 = *(const half8*)(Ypair + (size_t)p1 * HIDN + c0);
    half8 y2 = *(const half8*)(Ypair + (size_t)p2 * HIDN + c0);
    float* o = out + (size_t)t * HIDN + c0;
    floatx4 a = *(floatx4*)o, b = *(floatx4*)(o + 4);
#pragma unroll
    for (int j = 0; j < 4; ++j) {
        a[j] += (float)y1[j] + (float)y2[j];
        b[j] += (float)y1[4 + j] + (float)y2[4 + j];
    }
    *(floatx4*)o = a;
    *(floatx4*)(o + 4) = b;
}

// ---------------------------------------------------------------------------
extern "C" void kernel_launch(void* const* d_in, const int* in_sizes, int n_in,
                              void* d_out, int out_size, void* d_ws, size_t ws_size,
                              hipStream_t stream)
{
    (void)in_sizes; (void)n_in; (void)out_size; (void)ws_size;
    const float* x    = (const float*)d_in[0];
    const int*   pos  = (const int*)  d_in[1];
    const float* ln1w = (const float*)d_in[2];
    const float* qkvw = (const float*)d_in[3];
    const float* qkvb = (const float*)d_in[4];
    const float* klnw = (const float*)d_in[5];
    const float* ow   = (const float*)d_in[6];
    const float* ln2w = (const float*)d_in[7];
    const float* rw   = (const float*)d_in[8];
    const float* w1   = (const float*)d_in[9];
    const float* w2   = (const float*)d_in[10];
    const float* w3   = (const float*)d_in[11];
    const float* sw1  = (const float*)d_in[12];
    const float* sw2  = (const float*)d_in[13];
    const float* sw3  = (const float*)d_in[14];
    float* out = (float*)d_out;

    // ---- workspace arena (phase-overlapped; within proven 142.7 MB) ----
    char* ws = (char*)d_ws;
    const size_t AB = 16842752;
    float*  x2      = (float*)(ws);                   // also Opart1 (512 slots)
    half_t* h_hi    = (half_t*)(ws + AB);
    half_t* h_lo    = (half_t*)(ws + AB + 8388608);
    half_t* qkvwt_h = (half_t*)(ws + AB + 16777216);
    half_t* qkvwt_l = (half_t*)(ws + AB + 29360128);
    float*  qkv     = (float*)(ws + AB + 41943040);   // also Opart0 / W13t
    half_t* q_h     = (half_t*)(ws + AB + 67108864);
    half_t* q_l     = (half_t*)(ws + AB + 75497472);
    half_t* k_h     = (half_t*)(ws + AB + 83886080);
    half_t* k_l     = (half_t*)(ws + AB + 85983232);
    half_t* vt_h    = (half_t*)(ws + AB + 88080384);
    half_t* attn_h  = (half_t*)(ws + AB);             // reuse h_hi
    half_t* zt      = (half_t*)(ws + AB + 8388608);   // reuse h_lo (512 KB, f16)
    half_t* owt     = (half_t*)(ws + AB + 16777216);  // reuse qkvwt_h
    float*  ow_u    = (float*)(ws + AB + 25165824);   // 64 KB
    float*  mlpart  = (float*)(ws + AB + 25231360);   // 836 KB
    float*  Opart0  = (float*)(ws + AB + 41943040);   // qkv region, 768 slots
    float*  Opart1  = (float*)(ws);                   // x2 region, 512 slots
    float*  Opart2  = (float*)(ws + AB + 29360128);   // qkvwt_l region, 352 slots
    half_t* h2      = (half_t*)(ws + AB + 33554432);  // 8.4MB
    half_t* W13t    = (half_t*)(ws + AB + 41943040);  // 41.9MB (qkv+q dead)
    half_t* As_sh   = (half_t*)(ws + AB);             // 4.2MB (attn dead post-x2)
    half_t* Ab      = (half_t*)(ws + AB + 16777216);  // 4.7MB (owt dead)
    half_t* W2t     = (half_t*)(ws + AB + 41943040);  // 21MB (W13t dead post-GU)
    half_t* Ypair   = (half_t*)(ws + AB + 92274688);  // 18.9MB

    // ---- tail block: meta (~86KB) + zpart (3.34MB) + zfin (1MB) ----
    char* meta = ws + (size_t)(AB + 117440512);
    int*    cnt     = (int*)  (meta + 0);
    int*    basep   = (int*)  (meta + 128);
    int*    topi    = (int*)  (meta + 256);
    float*  topv    = (float*)(meta + 16640);
    int*    pairPos = (int*)  (meta + 33024);
    int*    pairTok = (int*)  (meta + 49408);
    float*  pairW   = (float*)(meta + 67840);
    float*  zpart   = (float*)(meta + 131072);        // 3342336 B
    float*  zfin    = (float*)(meta + 131072 + 3342336); // 1 MB

    dim3 b256(256);

    // 1. h = rmsnorm(x, ln1_w) split
    rmsnorm_split_k<<<T_TOK, b256, 0, stream>>>(x, ln1w, h_hi, h_lo);
    // 2. qkv_w -> transposed split f16
    transpose_split2<<<dim3(QKV_N / 32, HIDN / 32), b256, 0, stream>>>(
        qkvw, qkvwt_h, qkvwt_l, QKV_N, HIDN);
    // 3. qkv = h @ qkv_w + b  (split path, BM=128)
    gemm_f16<true, 128><<<dim3(QKV_N / 128, T_TOK / 128), b256, 0, stream>>>(
        h_hi, h_lo, qkvwt_h, qkvwt_l, qkvb, nullptr, qkv, nullptr,
        T_TOK, QKV_N, HIDN, HIDN, HIDN);
    // 4. k-rmsnorm + rope + split (q pre-scaled)
    qkv_prep<<<T_TOK, b256, 0, stream>>>(qkv, pos, klnw, q_h, q_l, k_h, k_l);
    // 5. v^T single f16, sigma-permuted
    vt_transpose_perm<<<dim3(512 / 64, T_TOK / 32), b256, 0, stream>>>(
        qkv + 2560, vt_h);
    // 6. o_w transpose (single f16)
    transpose_f16<<<dim3(HIDN / 64, HIDN / 32), b256, 0, stream>>>(
        ow, owt, HIDN, HIDN);
    // 7. ow_u = o_w @ (ln2w * rw)  (+ folded moe_init)
    owu_kernel<<<512, b256, 0, stream>>>(ow, ln2w, rw, ow_u,
                                         cnt, pairTok, pairW);
    // 7b. z moments -> f16 sigma-permuted zt[h*8+e][kv]
    z_kernel<<<T_TOK, b256, 0, stream>>>(qkv, ow_u, zt);
    // 8. attention (chunked, KVBLK=64, z folded into PV MFMA)
    attn_kernel<<<1632, b256, 0, stream>>>(
        q_h, q_l, k_h, k_l, vt_h, zt, attn_h,
        Opart0, Opart1, Opart2, mlpart, zpart, zfin);
    // 8b. combine partial chunks (O + z)
    attn_combine<<<416, b256, 0, stream>>>(Opart0, Opart1, Opart2, mlpart,
                                           zpart, attn_h, zfin);
    // 9. x2 = x + attn @ o_w  (single f16, BM=128)
    gemm_f16<false, 128><<<dim3(HIDN / 128, T_TOK / 128), b256, 0, stream>>>(
        attn_h, nullptr, owt, nullptr, nullptr, x, x2, nullptr,
        T_TOK, HIDN, HIDN, HIDN, HIDN);
    // 10. router (x.u + z moments) -> top-2 + h2
    router_linear<<<T_TOK, b256, 0, stream>>>(
        x, zfin, x2, ln2w, rw, topi, topv, cnt, h2);
    // 10b. deterministic pair-list build
    moe_build<<<NEXP, b256, 0, stream>>>(cnt, basep, topi, topv,
                                         pairTok, pairW, pairPos);
    // 11. W13t batched transpose
    w13_transpose<<<dim3(10240 / 64, HIDN / 32), b256, 0, stream>>>(
        sw1, w1, sw3, w3, W13t);
    // 12. fused GU + act, BM=64, shared + grouped in ONE launch (1088 blocks)
    gemm_gu_all<<<512 + 8 * (NPAIR_MAX / 64), b256, 0, stream>>>(
        h2, W13t, pairTok, basep, pairW, As_sh, Ab);
    // 13. W2t batched transpose
    w2_transpose<<<dim3(HIDN / 64, 5120 / 32), b256, 0, stream>>>(sw2, w2, W2t);
    // 14. fused down, BM=64 (shared -> out, grouped -> Ypair), grid (16,104)
    gemm_down_all<<<dim3(16, 104), b256, 0, stream>>>(
        As_sh, Ab, W2t, basep, x2, out, Ypair);
    // 15. out += Ypair[p1] + Ypair[p2]
    moe_final<<<T_TOK, b256, 0, stream>>>(Ypair, pairPos, out);
}